// Round 8
// baseline (257.574 us; speedup 1.0000x reference)
//
#include <hip/hip_runtime.h>
#include <math.h>

#ifndef __has_builtin
#define __has_builtin(x) 0
#endif
#if __has_builtin(__builtin_amdgcn_exp2f)
#define EXP2F(x) __builtin_amdgcn_exp2f(x)
#else
#define EXP2F(x) exp2f(x)
#endif

#define L2E  1.44269504088896340736f
#define RL2E 0.69314718055994530942f
#define GEXPC (-L2E / 72.0f)

#define NBATCH 2
#define NC 21
#define NP 4096
#define KR 35
#define NUM_ITER 5

typedef _Float16 half_t;
typedef _Float16 h8 __attribute__((ext_vector_type(8)));
typedef float f4 __attribute__((ext_vector_type(4)));
typedef float f2 __attribute__((ext_vector_type(2)));
#define MFMA16(a, b, c) __builtin_amdgcn_mfma_f32_16x16x32_f16((a), (b), (c), 0, 0, 0)

// packed fp32 math via inline asm (builtin lowering NaN'd — R8/R13)
static __device__ __forceinline__ f2 pk_fma(f2 a, f2 b, f2 c) {
    f2 d;
    asm volatile("v_pk_fma_f32 %0, %1, %2, %3" : "=v"(d) : "v"(a), "v"(b), "v"(c));
    return d;
}
static __device__ __forceinline__ f2 pk_add(f2 a, f2 b) {
    f2 d;
    asm volatile("v_pk_add_f32 %0, %1, %2" : "=v"(d) : "v"(a), "v"(b));
    return d;
}
static __device__ __forceinline__ f2 pk_mul(f2 a, f2 b) {
    f2 d;
    asm volatile("v_pk_mul_f32 %0, %1, %2" : "=v"(d) : "v"(a), "v"(b));
    return d;
}

// ---- mega tiling: block = (n, 16-p tile); wave v sweeps q in [v*1024,(v+1)*1024)
#define NPT 256                      // p-tiles per batch
#define NBMEGA (NBATCH * NPT)        // 512 blocks, 2/CU, barrier-free main loop
#define WSTEPS 32                    // 1024 q / 32 per step

// ---- ws layout (float offsets) ----
#define OFF_QFEAT 0                  // [8192][8] fp32 AoS {L*f0..L*f4, h, 0,0}
#define OFF_QSOA  65536              // [6][8192] fp32 SoA planes
#define OFF_UT    114688             // [8192][24] fp32 log-unary
#define OFF_QA    311296             // [2][32][4096] fp16 q ping (rows 21-31 zero)
#define OFF_QB    442368             // [2][32][4096] fp16 q pong (rows 21-31 zero)
#define OFF_G     573440             // 1 float: Cg = -2*log2(s)

__global__ __launch_bounds__(256) void setup_kernel(
    const float* __restrict__ unary, const float* __restrict__ ref,
    const float* __restrict__ kstd, float* __restrict__ ws)
{
    int gid = blockIdx.x * 256 + threadIdx.x;
    if (gid == 0) {
        float s = 0.f;
        for (int t = -KR; t <= KR; ++t) s += expf(-(float)(t * t) * (1.0f / 72.0f));
        ws[OFF_G] = -2.0f * log2f(s);      // G2d normalizer in log2 domain
    }
    if (gid >= NBATCH * NP) return;
    int n = gid >> 12, p = gid & (NP - 1);
    int y = p >> 6, x = p & 63;
    float k0 = kstd[0], k1 = kstd[1], k2 = kstd[2], k3 = kstd[3], k4 = kstd[4];
    const float* rp = ref + n * 3 * NP + p;
    float f0 = (float)y / k0;
    float f1 = (float)x / k1;
    float f2_ = rp[0]      / k2;
    float f3 = rp[NP]     / k3;
    float f4_ = rp[2 * NP] / k4;
    float sq = f0*f0 + f1*f1 + f2_*f2_ + f3*f3 + f4_*f4_;
    float h  = -0.5f * L2E * sq;
    float* qf = ws + OFF_QFEAT + gid * 8;
    qf[0]=L2E*f0; qf[1]=L2E*f1; qf[2]=L2E*f2_; qf[3]=L2E*f3; qf[4]=L2E*f4_;
    qf[5]=h; qf[6]=0.f; qf[7]=0.f;
    float* qs = ws + OFF_QSOA;
    qs[0*8192 + gid] = L2E*f0;  qs[1*8192 + gid] = L2E*f1;
    qs[2*8192 + gid] = L2E*f2_; qs[3*8192 + gid] = L2E*f3;
    qs[4*8192 + gid] = L2E*f4_; qs[5*8192 + gid] = h;

    float U[NC], e[NC];
    const float* up = unary + n * NC * NP + p;
    float m = -1e30f;
    for (int c = 0; c < NC; ++c) {
        float u = up[c * NP];
        u = fminf(fmaxf(u, 1e-5f), 1.0f);
        U[c] = logf(u);
        m = fmaxf(m, U[c]);
    }
    float ssum = 0.f;
    for (int c = 0; c < NC; ++c) { e[c] = EXP2F(L2E * (U[c] - m)); ssum += e[c]; }
    float inv = 1.0f / ssum;
    float* ut = ws + OFF_UT + gid * 24;
    half_t* qA = (half_t*)(ws + OFF_QA);
    half_t* qB = (half_t*)(ws + OFF_QB);
    for (int c = 0; c < NC; ++c) {
        ut[c] = U[c];
        qA[(size_t)(n * 32 + c) * NP + p] = (half_t)(e[c] * inv);
    }
    ut[21] = 0.f; ut[22] = 0.f; ut[23] = 0.f;
    // zero padding rows 21..31 of BOTH ping-pong buffers (epilogue never writes them)
    for (int c = NC; c < 32; ++c) {
        qA[(size_t)(n * 32 + c) * NP + p] = (half_t)0.f;
        qB[(size_t)(n * 32 + c) * NP + p] = (half_t)0.f;
    }
}

// ==========================================================================
// One dispatch per CRF iteration, barrier-free main loop.
// 512 blocks x 256 thr. Block (n, pt): 16 p-rows. Wave v: q in [v*1024,+1024).
// All operands read directly from global (L2-resident): qsoa features for the
// bilat exp chain (verbatim R10 kv math -> bit-identical K), q-probs as native
// MFMA B-fragments. Spatial conv folded as a SECOND MFMA with A = G2d
// fragments (dy hoisted per lane-step; band-clip omitted: err < 1e-7).
// fp32 accumulators end-to-end; one barrier; cross-wave LDS reduce; fused
// softmax epilogue writes qout (or outq on last iter). No partials, no conv
// blocks, no reduce dispatch. q ping-pongs across dispatches.
// ==========================================================================
__global__ __launch_bounds__(256) void crf_mega(
    const float* __restrict__ qfeatA,
    const float* __restrict__ qsoa,
    const half_t* __restrict__ qin,
    half_t* __restrict__ qout,
    const float* __restrict__ ut_,
    float* __restrict__ outq,
    const float* __restrict__ gconst,
    int last)
{
    __shared__ f4 redw[4][4][64];    // [wave][K0,K1,G0,G1][lane] 16 KB
    __shared__ f4 reds[4][64];       // summed                     4 KB

    int b = blockIdx.x;
    int n = b & 1, pt = b >> 1;
    int tid = threadIdx.x;
    int l = tid & 63, v = tid >> 6;
    int prow = l & 15, kq8 = (l >> 4) * 8;
    int p = pt * 16 + prow;
    int yp = p >> 6, xp = p & 63;

    const float* fp = qfeatA + (size_t)(n * NP + p) * 8;
    f2 pf2[5], ph2;
    #pragma unroll
    for (int i = 0; i < 5; ++i) { float vv = fp[i] * RL2E; pf2[i] = (f2){vv, vv}; }
    ph2 = (f2){fp[5], fp[5]};
    float Cg = gconst[0];
    f2 gc2 = (f2){GEXPC, GEXPC};

    const float*  qsb = qsoa + n * NP;
    const half_t* qb0 = qin + (size_t)(n * 32 + prow) * NP;
    const half_t* qb1 = qin + (size_t)(n * 32 + 16 + prow) * NP;

    f4 accK0 = (f4)0.f, accK1 = (f4)0.f, accG0 = (f4)0.f, accG1 = (f4)0.f;
    int vq = v * 1024;

    for (int step = 0; step < WSTEPS; ++step) {
        int qa = vq + step * 32 + kq8;            // this lane's 8-q base
        float dy = (float)(yp - (qa >> 6));       // same row for all 8 q's
        float bg = fmaf(dy * dy, GEXPC, Cg);
        f2 bg2 = (f2){bg, bg};
        int xq0 = qa & 63;
        h8 kv, gv;
        #pragma unroll
        for (int hf = 0; hf < 2; ++hf) {
            const float* qp = qsb + qa + hf * 4;
            f4 qf0 = *(const f4*)(qp + 0 * 8192);
            f4 qf1 = *(const f4*)(qp + 1 * 8192);
            f4 qf2 = *(const f4*)(qp + 2 * 8192);
            f4 qf3 = *(const f4*)(qp + 3 * 8192);
            f4 qf4 = *(const f4*)(qp + 4 * 8192);
            f4 qf5 = *(const f4*)(qp + 5 * 8192);
            #pragma unroll
            for (int pr = 0; pr < 2; ++pr) {
                f2 q0 = {qf0[2*pr], qf0[2*pr+1]};
                f2 q1 = {qf1[2*pr], qf1[2*pr+1]};
                f2 q2 = {qf2[2*pr], qf2[2*pr+1]};
                f2 q3 = {qf3[2*pr], qf3[2*pr+1]};
                f2 q4 = {qf4[2*pr], qf4[2*pr+1]};
                f2 qh2 = {qf5[2*pr], qf5[2*pr+1]};
                // bilat chain — verbatim R10 math (kv bit-identical)
                f2 e = pk_add(qh2, ph2);
                e = pk_fma(pf2[0], q0, e);
                e = pk_fma(pf2[1], q1, e);
                e = pk_fma(pf2[2], q2, e);
                e = pk_fma(pf2[3], q3, e);
                e = pk_fma(pf2[4], q4, e);
                // spatial G2d exponent (log2 domain)
                float dxa = (float)(xp - (xq0 + hf * 4 + pr * 2));
                f2 dxv = (f2){dxa, dxa - 1.0f};
                f2 es = pk_fma(pk_mul(dxv, dxv), gc2, bg2);
                int ix = hf * 4 + pr * 2;
                kv[ix]     = (half_t)EXP2F(e[0]);
                kv[ix + 1] = (half_t)EXP2F(e[1]);
                gv[ix]     = (half_t)EXP2F(es[0]);
                gv[ix + 1] = (half_t)EXP2F(es[1]);
            }
        }
        h8 bf0 = *(const h8*)(qb0 + qa);
        h8 bf1 = *(const h8*)(qb1 + qa);
        accK0 = MFMA16(kv, bf0, accK0);
        accK1 = MFMA16(kv, bf1, accK1);
        accG0 = MFMA16(gv, bf0, accG0);
        accG1 = MFMA16(gv, bf1, accG1);
    }

    // ---- cross-wave fp32 reduce (q-order preserved: w0+w1+w2+w3) ----
    redw[v][0][l] = accK0;
    redw[v][1][l] = accK1;
    redw[v][2][l] = accG0;
    redw[v][3][l] = accG1;
    __syncthreads();
    {
        int slot = tid >> 6, ll = tid & 63;
        f4 s = redw[0][slot][ll];
        s = s + redw[1][slot][ll];
        s = s + redw[2][slot][ll];
        s = s + redw[3][slot][ll];
        reds[slot][ll] = s;
    }
    __syncthreads();

    // ---- fused softmax for this block's 16 p's ----
    if (tid < 16) {
        int pp = tid;
        int pg = pt * 16 + pp;
        int gid = n * NP + pg;
        int lane0 = (pp >> 2) * 16, reg = pp & 3;
        const float* ut = ut_ + (size_t)gid * 24;
        float e[NC];
        float m = -1e30f;
        #pragma unroll
        for (int c = 0; c < NC; ++c) {
            int cht = c >> 4;
            float K = reds[cht][lane0 + (c & 15)][reg];
            float G = reds[2 + cht][lane0 + (c & 15)][reg];
            float li = ut[c] + 4.0f * K + 2.0f * G;
            e[c] = li;
            m = fmaxf(m, li);
        }
        float ssum = 0.f;
        #pragma unroll
        for (int c = 0; c < NC; ++c) { float vv = EXP2F(L2E * (e[c] - m)); e[c] = vv; ssum += vv; }
        float inv = 1.0f / ssum;
        if (last) {
            #pragma unroll
            for (int c = 0; c < NC; ++c)
                outq[(size_t)(n * NC + c) * NP + pg] = e[c] * inv;
        } else {
            #pragma unroll
            for (int c = 0; c < NC; ++c)
                qout[(size_t)(n * 32 + c) * NP + pg] = (half_t)(e[c] * inv);
        }
    }
}

extern "C" void kernel_launch(void* const* d_in, const int* in_sizes, int n_in,
                              void* d_out, int out_size, void* d_ws, size_t ws_size,
                              hipStream_t stream)
{
    const float* unary = (const float*)d_in[0];
    const float* ref   = (const float*)d_in[1];
    const float* kstd  = (const float*)d_in[3];
    float* ws   = (float*)d_ws;
    float* outq = (float*)d_out;

    const float* qfeatA = ws + OFF_QFEAT;
    const float* qsoa   = ws + OFF_QSOA;
    const float* ut     = ws + OFF_UT;
    half_t* qA = (half_t*)(ws + OFF_QA);
    half_t* qB = (half_t*)(ws + OFF_QB);
    const float* gconst = ws + OFF_G;

    setup_kernel<<<32, 256, 0, stream>>>(unary, ref, kstd, ws);
    for (int it = 0; it < NUM_ITER; ++it) {
        half_t* qin  = (it & 1) ? qB : qA;
        half_t* qout = (it & 1) ? qA : qB;
        crf_mega<<<NBMEGA, 256, 0, stream>>>(
            qfeatA, qsoa, qin, qout, ut, outq, gconst,
            it == NUM_ITER - 1 ? 1 : 0);
    }
}

// Round 10
// 206.736 us; speedup vs baseline: 1.2459x; 1.2459x over previous
//
#include <hip/hip_runtime.h>
#include <math.h>

#ifndef __has_builtin
#define __has_builtin(x) 0
#endif
#if __has_builtin(__builtin_amdgcn_exp2f)
#define EXP2F(x) __builtin_amdgcn_exp2f(x)
#else
#define EXP2F(x) exp2f(x)
#endif

#define L2E  1.44269504088896340736f
#define RL2E 0.69314718055994530942f

#define NBATCH 2
#define NC 21
#define NP 4096
#define KR 35
#define NUM_ITER 5

typedef _Float16 half_t;
typedef _Float16 h8 __attribute__((ext_vector_type(8)));
typedef _Float16 h4 __attribute__((ext_vector_type(4)));
typedef float f4 __attribute__((ext_vector_type(4)));
typedef float f2 __attribute__((ext_vector_type(2)));
#define MFMA16(a, b, c) __builtin_amdgcn_mfma_f32_16x16x32_f16((a), (b), (c), 0, 0, 0)

// packed fp32 math via inline asm (builtin lowering NaN'd — R8/R13)
static __device__ __forceinline__ f2 pk_fma(f2 a, f2 b, f2 c) {
    f2 d;
    asm volatile("v_pk_fma_f32 %0, %1, %2, %3" : "=v"(d) : "v"(a), "v"(b), "v"(c));
    return d;
}
static __device__ __forceinline__ f2 pk_add(f2 a, f2 b) {
    f2 d;
    asm volatile("v_pk_add_f32 %0, %1, %2" : "=v"(d) : "v"(a), "v"(b));
    return d;
}

// ---- tiling: R6-proven (PTILE=256, 4 m-tiles/wave) ----
#define PTILE 256
#define NPT   16
#define MTW   4
#define SQ    16
#define CHUNK 256
#define STEPS 8
#define NBBIL (NBATCH * NPT * SQ)   // 512
#define NBCONV (NBATCH * NC)        // 42 -> blocks [0,42) (conv FIRST: no tail)
#define NBTOT  (NBBIL + NBCONV)     // 554
#define SEG_HALVES 256

// ---- ws layout (float offsets; setup arrays deleted — computed inline) ----
#define OFF_QSF   311296             // [NB][21][P] fp32 spatial out
#define OFF_QH16  485376             // [NB][24][P] fp16 planar q
#define OFF_PART  845824             // [SQ][1024 segs][256] fp16 partials

#define LDS_BYTES 27648
#define QLS_STRIDE 264     // halves (256 data + 8 pad) — R6-proven banking

// ==========================================================================
// Fused per-iteration dispatch (NO setup kernel — all setup values are pure
// functions of inputs, computed inline bit-identically by their consumers).
// blocks [0,42): separable conv (first -> co-resident, no tail).
// blocks [42,554): bilateral, R6-verbatim inner loop & partial layout.
// ==========================================================================
__global__ __launch_bounds__(256) void bilat_conv_kernel(
    const float* __restrict__ unary,
    const float* __restrict__ ref,
    const float* __restrict__ kstd,
    const half_t* __restrict__ qh16,
    half_t* __restrict__ part,
    float* __restrict__ qsf,
    int first)
{
    __shared__ __align__(16) char lds[LDS_BYTES];
    int b = blockIdx.x;
    int tid = threadIdx.x;
    int l = tid & 63, w = tid >> 6;

    if (b >= NBCONV) {
        int bb = b - NBCONV;
        int n  = bb & 1;
        int pt = (bb >> 1) & (NPT - 1);            // 0..15
        int s  = bb >> 5;                          // 0..15
        float*  qsoaS = (float*)lds;               // [6][256]  6 KB
        half_t* qls   = (half_t*)(lds + 6144);     // [32][264] 16896 B

        float k0 = kstd[0], k1 = kstd[1], k2 = kstd[2], k3 = kstd[3], k4 = kstd[4];

        // q-side features computed inline (bit-identical to old setup math)
        {
            int pq = s * CHUNK + tid;              // this thread's chunk pixel
            int y = pq >> 6, x = pq & 63;
            const float* rp = ref + n * 3 * NP + pq;
            float f0 = (float)y / k0;
            float f1 = (float)x / k1;
            float f2_ = rp[0]      / k2;
            float f3 = rp[NP]     / k3;
            float f4_ = rp[2 * NP] / k4;
            float sq = f0*f0 + f1*f1 + f2_*f2_ + f3*f3 + f4_*f4_;
            float h  = -0.5f * L2E * sq;
            qsoaS[0 * CHUNK + tid] = L2E * f0;
            qsoaS[1 * CHUNK + tid] = L2E * f1;
            qsoaS[2 * CHUNK + tid] = L2E * f2_;
            qsoaS[3 * CHUNK + tid] = L2E * f3;
            qsoaS[4 * CHUNK + tid] = L2E * f4_;
            qsoaS[5 * CHUNK + tid] = h;
        }
        // q-probs rows 0..20: iter0 inline softmax, else stage from qh16
        if (first) {
            int pg = s * CHUNK + tid;
            const float* up = unary + (size_t)n * NC * NP + pg;
            float U[NC], e[NC];
            float m = -1e30f;
            for (int cc = 0; cc < NC; ++cc) {
                float u = up[cc * NP];
                u = fminf(fmaxf(u, 1e-5f), 1.0f);
                U[cc] = logf(u);
                m = fmaxf(m, U[cc]);
            }
            float ssum = 0.f;
            for (int cc = 0; cc < NC; ++cc) { e[cc] = EXP2F(L2E * (U[cc] - m)); ssum += e[cc]; }
            float inv = 1.0f / ssum;
            for (int cc = 0; cc < NC; ++cc)
                qls[cc * QLS_STRIDE + tid] = (half_t)(e[cc] * inv);
        } else {
            for (int i = tid; i < 21 * (CHUNK / 8); i += 256) {  // 672 h8
                int c = i >> 5, g = i & 31;
                *(h8*)(qls + c * QLS_STRIDE + g * 8) =
                    *(const h8*)(qh16 + (size_t)(n * 24 + c) * NP + s * CHUNK + g * 8);
            }
        }
        for (int i = tid; i < 11 * 33; i += 256) {           // 363 h8 zeros
            int c = 21 + i / 33, g = i % 33;
            *(h8*)(qls + c * QLS_STRIDE + g * 8) = (h8)(half_t)0.f;
        }
        // p-side features inline (replicates setup's qf=L2E*f then *RL2E rounding)
        f2 pf2[MTW][5], ph2[MTW];
        #pragma unroll
        for (int mt = 0; mt < MTW; ++mt) {
            int pp = pt * PTILE + (w * MTW + mt) * 16 + (l & 15);
            int y = pp >> 6, x = pp & 63;
            const float* rp = ref + n * 3 * NP + pp;
            float f[5];
            f[0] = (float)y / k0;
            f[1] = (float)x / k1;
            f[2] = rp[0]      / k2;
            f[3] = rp[NP]     / k3;
            f[4] = rp[2 * NP] / k4;
            float sq = f[0]*f[0] + f[1]*f[1] + f[2]*f[2] + f[3]*f[3] + f[4]*f[4];
            float h  = -0.5f * L2E * sq;
            #pragma unroll
            for (int i = 0; i < 5; ++i) {
                float qfv = L2E * f[i];        // setup's stored rounding
                float v = qfv * RL2E;          // R6's fp[i]*RL2E
                pf2[mt][i] = (f2){v, v};
            }
            ph2[mt] = (f2){h, h};
        }
        f4 acc[MTW][2];
        #pragma unroll
        for (int mt = 0; mt < MTW; ++mt) { acc[mt][0] = (f4)0.f; acc[mt][1] = (f4)0.f; }
        int kq = (l >> 4) * 8;
        __syncthreads();

        for (int step = 0; step < STEPS; ++step) {
            int qbase = step * 32 + kq;
            h8 kv[MTW];
            #pragma unroll
            for (int hf = 0; hf < 2; ++hf) {
                f4 qf0 = *(const f4*)(qsoaS + 0 * CHUNK + qbase + hf * 4);
                f4 qf1 = *(const f4*)(qsoaS + 1 * CHUNK + qbase + hf * 4);
                f4 qf2 = *(const f4*)(qsoaS + 2 * CHUNK + qbase + hf * 4);
                f4 qf3 = *(const f4*)(qsoaS + 3 * CHUNK + qbase + hf * 4);
                f4 qf4 = *(const f4*)(qsoaS + 4 * CHUNK + qbase + hf * 4);
                f4 qf5 = *(const f4*)(qsoaS + 5 * CHUNK + qbase + hf * 4);
                #pragma unroll
                for (int pr = 0; pr < 2; ++pr) {
                    f2 q0 = {qf0[2*pr], qf0[2*pr+1]};
                    f2 q1 = {qf1[2*pr], qf1[2*pr+1]};
                    f2 q2 = {qf2[2*pr], qf2[2*pr+1]};
                    f2 q3 = {qf3[2*pr], qf3[2*pr+1]};
                    f2 q4 = {qf4[2*pr], qf4[2*pr+1]};
                    f2 qh2 = {qf5[2*pr], qf5[2*pr+1]};
                    #pragma unroll
                    for (int mt = 0; mt < MTW; ++mt) {
                        f2 e = pk_add(qh2, ph2[mt]);
                        e = pk_fma(pf2[mt][0], q0, e);
                        e = pk_fma(pf2[mt][1], q1, e);
                        e = pk_fma(pf2[mt][2], q2, e);
                        e = pk_fma(pf2[mt][3], q3, e);
                        e = pk_fma(pf2[mt][4], q4, e);
                        kv[mt][hf * 4 + pr * 2]     = (half_t)EXP2F(e[0]);
                        kv[mt][hf * 4 + pr * 2 + 1] = (half_t)EXP2F(e[1]);
                    }
                }
            }
            h8 bf0 = *(const h8*)(qls + (size_t)(l & 15) * QLS_STRIDE + qbase);
            h8 bf1 = *(const h8*)(qls + (size_t)(16 + (l & 15)) * QLS_STRIDE + qbase);
            #pragma unroll
            for (int mt = 0; mt < MTW; ++mt) {
                acc[mt][0] = MFMA16(kv[mt], bf0, acc[mt][0]);
                acc[mt][1] = MFMA16(kv[mt], bf1, acc[mt][1]);
            }
        }
        // epilogue: raw C-fragment partials (R6 verbatim layout)
        #pragma unroll
        for (int mt = 0; mt < MTW; ++mt) {
            #pragma unroll
            for (int cht = 0; cht < 2; ++cht) {
                int segFlat = ((((s * 2 + n) * NPT + pt) * 4 + w) * MTW + mt) * 2 + cht;
                h4 hv;
                hv[0] = (half_t)acc[mt][cht][0];
                hv[1] = (half_t)acc[mt][cht][1];
                hv[2] = (half_t)acc[mt][cht][2];
                hv[3] = (half_t)acc[mt][cht][3];
                *(h4*)(part + (size_t)segFlat * SEG_HALVES + l * 4) = hv;
            }
        }
    } else {
        // ---- conv block: one (n,c); qsf = G * Q * G ----
        int n = b / NC, c = b % NC;
        half_t* qt = (half_t*)lds;
        half_t* gl = (half_t*)(lds + 9216);
        half_t* dl = (half_t*)(lds + 18432);

        // gmat inline (bit-identical to old setup: same s-sum order, same expf)
        {
            float s71 = 0.f;
            for (int t = -KR; t <= KR; ++t) s71 += expf(-(float)(t * t) * (1.0f / 72.0f));
            for (int i = tid; i < 512; i += 256) {
                int row = i >> 3, g = i & 7;
                h8 v;
                #pragma unroll
                for (int k = 0; k < 8; ++k) {
                    int col = g * 8 + k;
                    int d = row - col;
                    float vv = (d >= -KR && d <= KR)
                        ? expf(-(float)(d * d) * (1.0f / 72.0f)) / s71 : 0.f;
                    v[k] = (half_t)vv;
                }
                *(h8*)(gl + row * 72 + g * 8) = v;
            }
        }
        if (first) {
            // q0 inline: per-pixel 21-channel softmax (setup-identical math)
            for (int i = tid; i < 512; i += 256) {
                int row = i >> 3, g = i & 7;
                for (int k = 0; k < 8; ++k) {
                    int p = row * 64 + g * 8 + k;
                    const float* up = unary + (size_t)n * NC * NP + p;
                    float U[NC];
                    float m = -1e30f;
                    for (int cc = 0; cc < NC; ++cc) {
                        float u = up[cc * NP];
                        u = fminf(fmaxf(u, 1e-5f), 1.0f);
                        U[cc] = logf(u);
                        m = fmaxf(m, U[cc]);
                    }
                    float ssum = 0.f, ec = 0.f;
                    for (int cc = 0; cc < NC; ++cc) {
                        float e = EXP2F(L2E * (U[cc] - m));
                        ssum += e;
                        if (cc == c) ec = e;
                    }
                    float inv = 1.0f / ssum;
                    qt[(g * 8 + k) * 72 + row] = (half_t)(ec * inv);
                }
            }
        } else {
            const half_t* qsrc = qh16 + (size_t)(n * 24 + c) * NP;
            for (int i = tid; i < 512; i += 256) {
                int row = i >> 3, g = i & 7;
                h8 v = *(const h8*)(qsrc + row * 64 + g * 8);
                #pragma unroll
                for (int k = 0; k < 8; ++k) qt[(g * 8 + k) * 72 + row] = v[k];
            }
        }
        __syncthreads();

        int m0 = w * 16;
        f4 acc1[4];
        #pragma unroll
        for (int nt = 0; nt < 4; ++nt) acc1[nt] = (f4)0.f;
        #pragma unroll
        for (int ks = 0; ks < 2; ++ks) {
            h8 af = *(const h8*)(gl + (size_t)(m0 + (l & 15)) * 72 + ks * 32 + (l >> 4) * 8);
            #pragma unroll
            for (int nt = 0; nt < 4; ++nt) {
                h8 bf = *(const h8*)(qt + (size_t)(nt * 16 + (l & 15)) * 72 + ks * 32 + (l >> 4) * 8);
                acc1[nt] = MFMA16(af, bf, acc1[nt]);
            }
        }
        #pragma unroll
        for (int nt = 0; nt < 4; ++nt)
            #pragma unroll
            for (int r = 0; r < 4; ++r)
                dl[(size_t)(m0 + (l >> 4) * 4 + r) * 72 + nt * 16 + (l & 15)] = (half_t)acc1[nt][r];
        __syncthreads();

        f4 acc2[4];
        #pragma unroll
        for (int nt = 0; nt < 4; ++nt) acc2[nt] = (f4)0.f;
        #pragma unroll
        for (int ks = 0; ks < 2; ++ks) {
            h8 af = *(const h8*)(dl + (size_t)(m0 + (l & 15)) * 72 + ks * 32 + (l >> 4) * 8);
            #pragma unroll
            for (int nt = 0; nt < 4; ++nt) {
                h8 bf = *(const h8*)(gl + (size_t)(nt * 16 + (l & 15)) * 72 + ks * 32 + (l >> 4) * 8);
                acc2[nt] = MFMA16(af, bf, acc2[nt]);
            }
        }
        float* dst = qsf + (size_t)(n * NC + c) * NP;
        #pragma unroll
        for (int nt = 0; nt < 4; ++nt)
            #pragma unroll
            for (int r = 0; r < 4; ++r)
                dst[(size_t)(m0 + (l >> 4) * 4 + r) * 64 + nt * 16 + (l & 15)] = acc2[nt][r];
    }
}

// L2+L3 merged: reduce fp16 partials over s, then per-pixel softmax update.
// R6-verbatim except U computed inline from unary (bit-identical to setup).
__global__ __launch_bounds__(256) void reduce_update_kernel(
    const half_t* __restrict__ part, const float* __restrict__ unary,
    const float* __restrict__ qsf, float* __restrict__ outq,
    half_t* __restrict__ qh16, int last)
{
    __shared__ float red[1024];    // 4 segs * 256
    int rb = blockIdx.x;           // [0,256)
    int tid = threadIdx.x;
    int n = rb & 1, pt = (rb >> 1) & (NPT - 1), wq = rb >> 5;   // wq 0..7
    int w = wq >> 1, mtbase = (wq & 1) * 2;
    int lseg = tid >> 6, l = tid & 63;

    const half_t* pb = part
        + (size_t)(n * 512 + pt * 32 + w * 8 + mtbase * 2 + lseg) * SEG_HALVES
        + (size_t)l * 4;
    h4 vv[16];
    #pragma unroll
    for (int s = 0; s < SQ; ++s)
        vv[s] = *(const h4*)(pb + (size_t)s * 1024 * SEG_HALVES);

    float a0 = 0.f, a1 = 0.f, a2 = 0.f, a3 = 0.f;
    #pragma unroll
    for (int s = 0; s < SQ; ++s) {            // same s-order as R4/R6
        a0 += (float)vv[s][0]; a1 += (float)vv[s][1];
        a2 += (float)vv[s][2]; a3 += (float)vv[s][3];
    }
    *(f4*)(red + tid * 4) = (f4){a0, a1, a2, a3};
    __syncthreads();

    if (tid < 32) {
        int pp = tid;
        int p = pt * PTILE + wq * 32 + pp;
        int mtl = pp >> 4, mrow = pp & 15;
        int lg2 = mrow >> 2, reg = mrow & 3;

        const float* up = unary + (size_t)n * NC * NP + p;
        const float* qs = qsf + (size_t)n * NC * NP + p;
        float e[NC];
        float m = -1e30f;
        #pragma unroll
        for (int c = 0; c < NC; ++c) {
            float u = up[c * NP];
            u = fminf(fmaxf(u, 1e-5f), 1.0f);
            float U = logf(u);                 // bit-identical to old setup ut[c]
            int cht = c >> 4, chL = c & 15;
            float qb = red[(mtl * 2 + cht) * 256 + (lg2 * 16 + chL) * 4 + reg];
            float li = U + 4.0f * qb + 2.0f * qs[c * NP];
            e[c] = li;
            m = fmaxf(m, li);
        }
        float ssum = 0.f;
        #pragma unroll
        for (int c = 0; c < NC; ++c) { float v = EXP2F(L2E * (e[c] - m)); e[c] = v; ssum += v; }
        float inv = 1.0f / ssum;
        if (last) {
            #pragma unroll
            for (int c = 0; c < NC; ++c)
                outq[(size_t)(n * NC + c) * NP + p] = e[c] * inv;
        } else {
            #pragma unroll
            for (int c = 0; c < NC; ++c)
                qh16[(size_t)(n * 24 + c) * NP + p] = (half_t)(e[c] * inv);
        }
    }
}

extern "C" void kernel_launch(void* const* d_in, const int* in_sizes, int n_in,
                              void* d_out, int out_size, void* d_ws, size_t ws_size,
                              hipStream_t stream)
{
    const float* unary = (const float*)d_in[0];
    const float* ref   = (const float*)d_in[1];
    const float* kstd  = (const float*)d_in[3];
    float* ws   = (float*)d_ws;
    float* outq = (float*)d_out;

    float*  qsf  = ws + OFF_QSF;
    half_t* qh16 = (half_t*)(ws + OFF_QH16);
    half_t* part = (half_t*)(ws + OFF_PART);

    for (int it = 0; it < NUM_ITER; ++it) {
        bilat_conv_kernel<<<NBTOT, 256, 0, stream>>>(
            unary, ref, kstd, qh16, part, qsf, it == 0 ? 1 : 0);
        reduce_update_kernel<<<256, 256, 0, stream>>>(
            part, unary, qsf, outq, qh16, it == NUM_ITER - 1 ? 1 : 0);
    }
}

// Round 11
// 184.427 us; speedup vs baseline: 1.3966x; 1.1210x over previous
//
#include <hip/hip_runtime.h>
#include <math.h>

#ifndef __has_builtin
#define __has_builtin(x) 0
#endif
#if __has_builtin(__builtin_amdgcn_exp2f)
#define EXP2F(x) __builtin_amdgcn_exp2f(x)
#else
#define EXP2F(x) exp2f(x)
#endif

#define L2E  1.44269504088896340736f
#define RL2E 0.69314718055994530942f

#define NBATCH 2
#define NC 21
#define NP 4096
#define KR 35
#define NUM_ITER 5

typedef _Float16 half_t;
typedef _Float16 h8 __attribute__((ext_vector_type(8)));
typedef _Float16 h4 __attribute__((ext_vector_type(4)));
typedef float f4 __attribute__((ext_vector_type(4)));
typedef float f2 __attribute__((ext_vector_type(2)));
#define MFMA16(a, b, c) __builtin_amdgcn_mfma_f32_16x16x32_f16((a), (b), (c), 0, 0, 0)

// packed fp32 math via inline asm (builtin lowering NaN'd — R8/R13)
static __device__ __forceinline__ f2 pk_fma(f2 a, f2 b, f2 c) {
    f2 d;
    asm volatile("v_pk_fma_f32 %0, %1, %2, %3" : "=v"(d) : "v"(a), "v"(b), "v"(c));
    return d;
}
static __device__ __forceinline__ f2 pk_add(f2 a, f2 b) {
    f2 d;
    asm volatile("v_pk_add_f32 %0, %1, %2" : "=v"(d) : "v"(a), "v"(b));
    return d;
}

// ---- tiling: R6-proven (PTILE=256, 4 m-tiles/wave) ----
#define PTILE 256
#define NPT   16
#define MTW   4
#define SQ    16
#define CHUNK 256
#define STEPS 8
#define NBBIL (NBATCH * NPT * SQ)   // 512
#define NBCONV (NBATCH * NC)        // 42 (blocks [512,554): conv LAST, as R6)
#define NBTOT  (NBBIL + NBCONV)     // 554
#define SEG_HALVES 256

// ---- ws layout (float offsets; UT slot now unused) ----
#define OFF_QFEAT 0                  // [8192][8] fp32 AoS p-features
#define OFF_QSOA  65536              // [6][8192] fp32 SoA q-feature planes
#define OFF_QSF   311296             // [NB][21][P] fp32 spatial out
#define OFF_G     483328             // [64][64] fp16 band-gaussian
#define OFF_QH16  485376             // [NB][24][P] fp16 planar q
#define OFF_PART  845824             // [SQ][1024 segs][256] fp16 partials

#define LDS_BYTES 27648
#define QLS_STRIDE 264     // halves (256 data + 8 pad) — R6-proven banking

// ==========================================================================
// Kernel A — iteration 0 ONLY (separate kernel => isolated regalloc).
// Computes all former-setup values inline; persists qsoa/qfeat/gmat for
// iterations 1-4. Main loops are R6-verbatim.
// ==========================================================================
__global__ __launch_bounds__(256, 2) void iter0_kernel(
    const float* __restrict__ unary,
    const float* __restrict__ ref,
    const float* __restrict__ kstd,
    half_t* __restrict__ part,
    float* __restrict__ qsf,
    float* __restrict__ qsoa,
    float* __restrict__ qfeat,
    half_t* __restrict__ gmat)
{
    __shared__ __align__(16) char lds[LDS_BYTES];
    int b = blockIdx.x;
    int tid = threadIdx.x;
    int l = tid & 63, w = tid >> 6;

    if (b < NBBIL) {
        int n  = b & 1;
        int pt = (b >> 1) & (NPT - 1);             // 0..15
        int s  = b >> 5;                           // 0..15
        float*  qsoaS = (float*)lds;               // [6][256]
        half_t* qls   = (half_t*)(lds + 6144);     // [32][264]

        float k0 = kstd[0], k1 = kstd[1], k2 = kstd[2], k3 = kstd[3], k4 = kstd[4];

        // ---- q-side features inline (setup-identical expressions) ----
        {
            int pq = s * CHUNK + tid;
            int y = pq >> 6, x = pq & 63;
            const float* rp = ref + n * 3 * NP + pq;
            float f0 = (float)y / k0;
            float f1 = (float)x / k1;
            float f2_ = rp[0]      / k2;
            float f3 = rp[NP]     / k3;
            float f4_ = rp[2 * NP] / k4;
            float sq = f0*f0 + f1*f1 + f2_*f2_ + f3*f3 + f4_*f4_;
            float h  = -0.5f * L2E * sq;
            float v0 = L2E * f0, v1 = L2E * f1, v2 = L2E * f2_;
            float v3 = L2E * f3, v4 = L2E * f4_;
            qsoaS[0 * CHUNK + tid] = v0;
            qsoaS[1 * CHUNK + tid] = v1;
            qsoaS[2 * CHUNK + tid] = v2;
            qsoaS[3 * CHUNK + tid] = v3;
            qsoaS[4 * CHUNK + tid] = v4;
            qsoaS[5 * CHUNK + tid] = h;
            if (pt == 0) {                          // persist chunk s (unique writer)
                int gid = n * NP + pq;
                qsoa[0 * 8192 + gid] = v0;  qsoa[1 * 8192 + gid] = v1;
                qsoa[2 * 8192 + gid] = v2;  qsoa[3 * 8192 + gid] = v3;
                qsoa[4 * 8192 + gid] = v4;  qsoa[5 * 8192 + gid] = h;
            }
        }
        // ---- q0 inline, 3-pass LDS-scratch softmax (no register arrays) ----
        {
            int pg = s * CHUNK + tid;
            const float* up = unary + (size_t)n * NC * NP + pg;
            float m = -1e30f;
            for (int cc = 0; cc < NC; ++cc) {
                float u = fminf(fmaxf(up[cc * NP], 1e-5f), 1.0f);
                m = fmaxf(m, logf(u));
            }
            float ssum = 0.f;
            for (int cc = 0; cc < NC; ++cc) {
                float u = fminf(fmaxf(up[cc * NP], 1e-5f), 1.0f);
                float e = EXP2F(L2E * (logf(u) - m));
                qls[cc * QLS_STRIDE + tid] = (half_t)e;
                ssum += e;
            }
            float inv = 1.0f / ssum;
            for (int cc = 0; cc < NC; ++cc)
                qls[cc * QLS_STRIDE + tid] =
                    (half_t)((float)qls[cc * QLS_STRIDE + tid] * inv);
        }
        for (int i = tid; i < 11 * 33; i += 256) {
            int c = 21 + i / 33, g = i % 33;
            *(h8*)(qls + c * QLS_STRIDE + g * 8) = (h8)(half_t)0.f;
        }
        // ---- p-side features inline (setup's L2E*f then *RL2E rounding) ----
        f2 pf2[MTW][5], ph2[MTW];
        #pragma unroll
        for (int mt = 0; mt < MTW; ++mt) {
            int pp = pt * PTILE + (w * MTW + mt) * 16 + (l & 15);
            int y = pp >> 6, x = pp & 63;
            const float* rp = ref + n * 3 * NP + pp;
            float f[5];
            f[0] = (float)y / k0;
            f[1] = (float)x / k1;
            f[2] = rp[0]      / k2;
            f[3] = rp[NP]     / k3;
            f[4] = rp[2 * NP] / k4;
            float sq = f[0]*f[0] + f[1]*f[1] + f[2]*f[2] + f[3]*f[3] + f[4]*f[4];
            float h  = -0.5f * L2E * sq;
            #pragma unroll
            for (int i = 0; i < 5; ++i) {
                float qfv = L2E * f[i];
                float v = qfv * RL2E;
                pf2[mt][i] = (f2){v, v};
            }
            ph2[mt] = (f2){h, h};
            if (s == 0 && l < 16) {                 // persist p-features (unique writer)
                float* qf = qfeat + (size_t)(n * NP + pp) * 8;
                #pragma unroll
                for (int i = 0; i < 5; ++i) qf[i] = L2E * f[i];
                qf[5] = h; qf[6] = 0.f; qf[7] = 0.f;
            }
        }
        f4 acc[MTW][2];
        #pragma unroll
        for (int mt = 0; mt < MTW; ++mt) { acc[mt][0] = (f4)0.f; acc[mt][1] = (f4)0.f; }
        int kq = (l >> 4) * 8;
        __syncthreads();

        for (int step = 0; step < STEPS; ++step) {
            int qbase = step * 32 + kq;
            h8 kv[MTW];
            #pragma unroll
            for (int hf = 0; hf < 2; ++hf) {
                f4 qf0 = *(const f4*)(qsoaS + 0 * CHUNK + qbase + hf * 4);
                f4 qf1 = *(const f4*)(qsoaS + 1 * CHUNK + qbase + hf * 4);
                f4 qf2 = *(const f4*)(qsoaS + 2 * CHUNK + qbase + hf * 4);
                f4 qf3 = *(const f4*)(qsoaS + 3 * CHUNK + qbase + hf * 4);
                f4 qf4 = *(const f4*)(qsoaS + 4 * CHUNK + qbase + hf * 4);
                f4 qf5 = *(const f4*)(qsoaS + 5 * CHUNK + qbase + hf * 4);
                #pragma unroll
                for (int pr = 0; pr < 2; ++pr) {
                    f2 q0 = {qf0[2*pr], qf0[2*pr+1]};
                    f2 q1 = {qf1[2*pr], qf1[2*pr+1]};
                    f2 q2 = {qf2[2*pr], qf2[2*pr+1]};
                    f2 q3 = {qf3[2*pr], qf3[2*pr+1]};
                    f2 q4 = {qf4[2*pr], qf4[2*pr+1]};
                    f2 qh2 = {qf5[2*pr], qf5[2*pr+1]};
                    #pragma unroll
                    for (int mt = 0; mt < MTW; ++mt) {
                        f2 e = pk_add(qh2, ph2[mt]);
                        e = pk_fma(pf2[mt][0], q0, e);
                        e = pk_fma(pf2[mt][1], q1, e);
                        e = pk_fma(pf2[mt][2], q2, e);
                        e = pk_fma(pf2[mt][3], q3, e);
                        e = pk_fma(pf2[mt][4], q4, e);
                        kv[mt][hf * 4 + pr * 2]     = (half_t)EXP2F(e[0]);
                        kv[mt][hf * 4 + pr * 2 + 1] = (half_t)EXP2F(e[1]);
                    }
                }
            }
            h8 bf0 = *(const h8*)(qls + (size_t)(l & 15) * QLS_STRIDE + qbase);
            h8 bf1 = *(const h8*)(qls + (size_t)(16 + (l & 15)) * QLS_STRIDE + qbase);
            #pragma unroll
            for (int mt = 0; mt < MTW; ++mt) {
                acc[mt][0] = MFMA16(kv[mt], bf0, acc[mt][0]);
                acc[mt][1] = MFMA16(kv[mt], bf1, acc[mt][1]);
            }
        }
        #pragma unroll
        for (int mt = 0; mt < MTW; ++mt) {
            #pragma unroll
            for (int cht = 0; cht < 2; ++cht) {
                int segFlat = ((((s * 2 + n) * NPT + pt) * 4 + w) * MTW + mt) * 2 + cht;
                h4 hv;
                hv[0] = (half_t)acc[mt][cht][0];
                hv[1] = (half_t)acc[mt][cht][1];
                hv[2] = (half_t)acc[mt][cht][2];
                hv[3] = (half_t)acc[mt][cht][3];
                *(h4*)(part + (size_t)segFlat * SEG_HALVES + l * 4) = hv;
            }
        }
    } else {
        // ---- conv block iter0: gmat + q0 inline; MFMA pipeline R6-verbatim ----
        int cb = b - NBBIL;
        int n = cb / NC, c = cb % NC;
        half_t* qt = (half_t*)lds;
        half_t* gl = (half_t*)(lds + 9216);
        half_t* dl = (half_t*)(lds + 18432);

        {
            float s71 = 0.f;
            for (int t = -KR; t <= KR; ++t) s71 += expf(-(float)(t * t) * (1.0f / 72.0f));
            for (int i = tid; i < 512; i += 256) {
                int row = i >> 3, g = i & 7;
                h8 v;
                #pragma unroll
                for (int k = 0; k < 8; ++k) {
                    int col = g * 8 + k;
                    int d = row - col;
                    float vv = (d >= -KR && d <= KR)
                        ? expf(-(float)(d * d) * (1.0f / 72.0f)) / s71 : 0.f;
                    v[k] = (half_t)vv;
                }
                *(h8*)(gl + row * 72 + g * 8) = v;
                if (cb == 0)                         // persist gmat (unique writer)
                    *(h8*)(gmat + row * 64 + g * 8) = v;
            }
        }
        // q0 inline: 3-pass per pixel, LDS-scratch (qt) for e values
        for (int i = tid; i < 512; i += 256) {
            int row = i >> 3, g = i & 7;
            for (int k = 0; k < 8; ++k) {
                int p = row * 64 + g * 8 + k;
                const float* up = unary + (size_t)n * NC * NP + p;
                float m = -1e30f;
                for (int cc = 0; cc < NC; ++cc) {
                    float u = fminf(fmaxf(up[cc * NP], 1e-5f), 1.0f);
                    m = fmaxf(m, logf(u));
                }
                float ssum = 0.f, ec = 0.f;
                for (int cc = 0; cc < NC; ++cc) {
                    float u = fminf(fmaxf(up[cc * NP], 1e-5f), 1.0f);
                    float e = EXP2F(L2E * (logf(u) - m));
                    ssum += e;
                    if (cc == c) ec = e;
                }
                qt[(g * 8 + k) * 72 + row] = (half_t)(ec / ssum);
            }
        }
        __syncthreads();

        int m0 = w * 16;
        f4 acc1[4];
        #pragma unroll
        for (int nt = 0; nt < 4; ++nt) acc1[nt] = (f4)0.f;
        #pragma unroll
        for (int ks = 0; ks < 2; ++ks) {
            h8 af = *(const h8*)(gl + (size_t)(m0 + (l & 15)) * 72 + ks * 32 + (l >> 4) * 8);
            #pragma unroll
            for (int nt = 0; nt < 4; ++nt) {
                h8 bf = *(const h8*)(qt + (size_t)(nt * 16 + (l & 15)) * 72 + ks * 32 + (l >> 4) * 8);
                acc1[nt] = MFMA16(af, bf, acc1[nt]);
            }
        }
        #pragma unroll
        for (int nt = 0; nt < 4; ++nt)
            #pragma unroll
            for (int r = 0; r < 4; ++r)
                dl[(size_t)(m0 + (l >> 4) * 4 + r) * 72 + nt * 16 + (l & 15)] = (half_t)acc1[nt][r];
        __syncthreads();

        f4 acc2[4];
        #pragma unroll
        for (int nt = 0; nt < 4; ++nt) acc2[nt] = (f4)0.f;
        #pragma unroll
        for (int ks = 0; ks < 2; ++ks) {
            h8 af = *(const h8*)(dl + (size_t)(m0 + (l & 15)) * 72 + ks * 32 + (l >> 4) * 8);
            #pragma unroll
            for (int nt = 0; nt < 4; ++nt) {
                h8 bf = *(const h8*)(gl + (size_t)(nt * 16 + (l & 15)) * 72 + ks * 32 + (l >> 4) * 8);
                acc2[nt] = MFMA16(af, bf, acc2[nt]);
            }
        }
        float* dst = qsf + (size_t)(n * NC + c) * NP;
        #pragma unroll
        for (int nt = 0; nt < 4; ++nt)
            #pragma unroll
            for (int r = 0; r < 4; ++r)
                dst[(size_t)(m0 + (l >> 4) * 4 + r) * 64 + nt * 16 + (l & 15)] = acc2[nt][r];
    }
}

// ==========================================================================
// Kernel B — iterations 1..4, R6-VERBATIM (staged operands, proven 144.4).
// ==========================================================================
__global__ __launch_bounds__(256) void bilat_conv_kernel(
    const float* __restrict__ qfeatA,
    const float* __restrict__ qsoa,
    const half_t* __restrict__ qh16,
    const half_t* __restrict__ gmat,
    half_t* __restrict__ part,
    float* __restrict__ qsf)
{
    __shared__ __align__(16) char lds[LDS_BYTES];
    int b = blockIdx.x;
    int tid = threadIdx.x;
    int l = tid & 63, w = tid >> 6;

    if (b < NBBIL) {
        int n  = b & 1;
        int pt = (b >> 1) & (NPT - 1);
        int s  = b >> 5;
        float*  qsoaS = (float*)lds;
        half_t* qls   = (half_t*)(lds + 6144);

        for (int i = tid; i < 6 * (CHUNK / 4); i += 256) {
            int d = i >> 6, g = i & 63;
            *(f4*)(qsoaS + d * CHUNK + g * 4) =
                *(const f4*)(qsoa + (size_t)d * 8192 + n * NP + s * CHUNK + g * 4);
        }
        for (int i = tid; i < 21 * (CHUNK / 8); i += 256) {
            int c = i >> 5, g = i & 31;
            *(h8*)(qls + c * QLS_STRIDE + g * 8) =
                *(const h8*)(qh16 + (size_t)(n * 24 + c) * NP + s * CHUNK + g * 8);
        }
        for (int i = tid; i < 11 * 33; i += 256) {
            int c = 21 + i / 33, g = i % 33;
            *(h8*)(qls + c * QLS_STRIDE + g * 8) = (h8)(half_t)0.f;
        }
        f2 pf2[MTW][5], ph2[MTW];
        #pragma unroll
        for (int mt = 0; mt < MTW; ++mt) {
            const float* fp = qfeatA + (size_t)(n * NP + pt * PTILE + (w * MTW + mt) * 16 + (l & 15)) * 8;
            #pragma unroll
            for (int i = 0; i < 5; ++i) {
                float v = fp[i] * RL2E;
                pf2[mt][i] = (f2){v, v};
            }
            ph2[mt] = (f2){fp[5], fp[5]};
        }
        f4 acc[MTW][2];
        #pragma unroll
        for (int mt = 0; mt < MTW; ++mt) { acc[mt][0] = (f4)0.f; acc[mt][1] = (f4)0.f; }
        int kq = (l >> 4) * 8;
        __syncthreads();

        for (int step = 0; step < STEPS; ++step) {
            int qbase = step * 32 + kq;
            h8 kv[MTW];
            #pragma unroll
            for (int hf = 0; hf < 2; ++hf) {
                f4 qf0 = *(const f4*)(qsoaS + 0 * CHUNK + qbase + hf * 4);
                f4 qf1 = *(const f4*)(qsoaS + 1 * CHUNK + qbase + hf * 4);
                f4 qf2 = *(const f4*)(qsoaS + 2 * CHUNK + qbase + hf * 4);
                f4 qf3 = *(const f4*)(qsoaS + 3 * CHUNK + qbase + hf * 4);
                f4 qf4 = *(const f4*)(qsoaS + 4 * CHUNK + qbase + hf * 4);
                f4 qf5 = *(const f4*)(qsoaS + 5 * CHUNK + qbase + hf * 4);
                #pragma unroll
                for (int pr = 0; pr < 2; ++pr) {
                    f2 q0 = {qf0[2*pr], qf0[2*pr+1]};
                    f2 q1 = {qf1[2*pr], qf1[2*pr+1]};
                    f2 q2 = {qf2[2*pr], qf2[2*pr+1]};
                    f2 q3 = {qf3[2*pr], qf3[2*pr+1]};
                    f2 q4 = {qf4[2*pr], qf4[2*pr+1]};
                    f2 qh2 = {qf5[2*pr], qf5[2*pr+1]};
                    #pragma unroll
                    for (int mt = 0; mt < MTW; ++mt) {
                        f2 e = pk_add(qh2, ph2[mt]);
                        e = pk_fma(pf2[mt][0], q0, e);
                        e = pk_fma(pf2[mt][1], q1, e);
                        e = pk_fma(pf2[mt][2], q2, e);
                        e = pk_fma(pf2[mt][3], q3, e);
                        e = pk_fma(pf2[mt][4], q4, e);
                        kv[mt][hf * 4 + pr * 2]     = (half_t)EXP2F(e[0]);
                        kv[mt][hf * 4 + pr * 2 + 1] = (half_t)EXP2F(e[1]);
                    }
                }
            }
            h8 bf0 = *(const h8*)(qls + (size_t)(l & 15) * QLS_STRIDE + qbase);
            h8 bf1 = *(const h8*)(qls + (size_t)(16 + (l & 15)) * QLS_STRIDE + qbase);
            #pragma unroll
            for (int mt = 0; mt < MTW; ++mt) {
                acc[mt][0] = MFMA16(kv[mt], bf0, acc[mt][0]);
                acc[mt][1] = MFMA16(kv[mt], bf1, acc[mt][1]);
            }
        }
        #pragma unroll
        for (int mt = 0; mt < MTW; ++mt) {
            #pragma unroll
            for (int cht = 0; cht < 2; ++cht) {
                int segFlat = ((((s * 2 + n) * NPT + pt) * 4 + w) * MTW + mt) * 2 + cht;
                h4 hv;
                hv[0] = (half_t)acc[mt][cht][0];
                hv[1] = (half_t)acc[mt][cht][1];
                hv[2] = (half_t)acc[mt][cht][2];
                hv[3] = (half_t)acc[mt][cht][3];
                *(h4*)(part + (size_t)segFlat * SEG_HALVES + l * 4) = hv;
            }
        }
    } else {
        int cb = b - NBBIL;
        int n = cb / NC, c = cb % NC;
        half_t* qt = (half_t*)lds;
        half_t* gl = (half_t*)(lds + 9216);
        half_t* dl = (half_t*)(lds + 18432);

        for (int i = tid; i < 512; i += 256) {
            int row = i >> 3, g = i & 7;
            *(h8*)(gl + row * 72 + g * 8) = *(const h8*)(gmat + row * 64 + g * 8);
        }
        const half_t* qsrc = qh16 + (size_t)(n * 24 + c) * NP;
        for (int i = tid; i < 512; i += 256) {
            int row = i >> 3, g = i & 7;
            h8 v = *(const h8*)(qsrc + row * 64 + g * 8);
            #pragma unroll
            for (int k = 0; k < 8; ++k) qt[(g * 8 + k) * 72 + row] = v[k];
        }
        __syncthreads();

        int m0 = w * 16;
        f4 acc1[4];
        #pragma unroll
        for (int nt = 0; nt < 4; ++nt) acc1[nt] = (f4)0.f;
        #pragma unroll
        for (int ks = 0; ks < 2; ++ks) {
            h8 af = *(const h8*)(gl + (size_t)(m0 + (l & 15)) * 72 + ks * 32 + (l >> 4) * 8);
            #pragma unroll
            for (int nt = 0; nt < 4; ++nt) {
                h8 bf = *(const h8*)(qt + (size_t)(nt * 16 + (l & 15)) * 72 + ks * 32 + (l >> 4) * 8);
                acc1[nt] = MFMA16(af, bf, acc1[nt]);
            }
        }
        #pragma unroll
        for (int nt = 0; nt < 4; ++nt)
            #pragma unroll
            for (int r = 0; r < 4; ++r)
                dl[(size_t)(m0 + (l >> 4) * 4 + r) * 72 + nt * 16 + (l & 15)] = (half_t)acc1[nt][r];
        __syncthreads();

        f4 acc2[4];
        #pragma unroll
        for (int nt = 0; nt < 4; ++nt) acc2[nt] = (f4)0.f;
        #pragma unroll
        for (int ks = 0; ks < 2; ++ks) {
            h8 af = *(const h8*)(dl + (size_t)(m0 + (l & 15)) * 72 + ks * 32 + (l >> 4) * 8);
            #pragma unroll
            for (int nt = 0; nt < 4; ++nt) {
                h8 bf = *(const h8*)(gl + (size_t)(nt * 16 + (l & 15)) * 72 + ks * 32 + (l >> 4) * 8);
                acc2[nt] = MFMA16(af, bf, acc2[nt]);
            }
        }
        float* dst = qsf + (size_t)(n * NC + c) * NP;
        #pragma unroll
        for (int nt = 0; nt < 4; ++nt)
            #pragma unroll
            for (int r = 0; r < 4; ++r)
                dst[(size_t)(m0 + (l >> 4) * 4 + r) * 64 + nt * 16 + (l & 15)] = acc2[nt][r];
    }
}

// ==========================================================================
// Kernel C — reduce + softmax (R6-verbatim mapping; U inlined from unary).
// ==========================================================================
__global__ __launch_bounds__(256) void reduce_update_kernel(
    const half_t* __restrict__ part, const float* __restrict__ unary,
    const float* __restrict__ qsf, float* __restrict__ outq,
    half_t* __restrict__ qh16, int last)
{
    __shared__ float red[1024];
    int rb = blockIdx.x;           // [0,256)
    int tid = threadIdx.x;
    int n = rb & 1, pt = (rb >> 1) & (NPT - 1), wq = rb >> 5;   // wq 0..7
    int w = wq >> 1, mtbase = (wq & 1) * 2;
    int lseg = tid >> 6, l = tid & 63;

    const half_t* pb = part
        + (size_t)(n * 512 + pt * 32 + w * 8 + mtbase * 2 + lseg) * SEG_HALVES
        + (size_t)l * 4;
    h4 vv[16];
    #pragma unroll
    for (int s = 0; s < SQ; ++s)
        vv[s] = *(const h4*)(pb + (size_t)s * 1024 * SEG_HALVES);

    float a0 = 0.f, a1 = 0.f, a2 = 0.f, a3 = 0.f;
    #pragma unroll
    for (int s = 0; s < SQ; ++s) {
        a0 += (float)vv[s][0]; a1 += (float)vv[s][1];
        a2 += (float)vv[s][2]; a3 += (float)vv[s][3];
    }
    *(f4*)(red + tid * 4) = (f4){a0, a1, a2, a3};
    __syncthreads();

    if (tid < 32) {
        int pp = tid;
        int p = pt * PTILE + wq * 32 + pp;
        int mtl = pp >> 4, mrow = pp & 15;
        int lg2 = mrow >> 2, reg = mrow & 3;

        const float* up = unary + (size_t)n * NC * NP + p;
        const float* qs = qsf + (size_t)n * NC * NP + p;
        float e[NC];
        float m = -1e30f;
        #pragma unroll
        for (int c = 0; c < NC; ++c) {
            float u = fminf(fmaxf(up[c * NP], 1e-5f), 1.0f);
            float U = logf(u);
            int cht = c >> 4, chL = c & 15;
            float qb = red[(mtl * 2 + cht) * 256 + (lg2 * 16 + chL) * 4 + reg];
            float li = U + 4.0f * qb + 2.0f * qs[c * NP];
            e[c] = li;
            m = fmaxf(m, li);
        }
        float ssum = 0.f;
        #pragma unroll
        for (int c = 0; c < NC; ++c) { float v = EXP2F(L2E * (e[c] - m)); e[c] = v; ssum += v; }
        float inv = 1.0f / ssum;
        if (last) {
            #pragma unroll
            for (int c = 0; c < NC; ++c)
                outq[(size_t)(n * NC + c) * NP + p] = e[c] * inv;
        } else {
            #pragma unroll
            for (int c = 0; c < NC; ++c)
                qh16[(size_t)(n * 24 + c) * NP + p] = (half_t)(e[c] * inv);
        }
    }
}

extern "C" void kernel_launch(void* const* d_in, const int* in_sizes, int n_in,
                              void* d_out, int out_size, void* d_ws, size_t ws_size,
                              hipStream_t stream)
{
    const float* unary = (const float*)d_in[0];
    const float* ref   = (const float*)d_in[1];
    const float* kstd  = (const float*)d_in[3];
    float* ws   = (float*)d_ws;
    float* outq = (float*)d_out;

    float*  qfeat = ws + OFF_QFEAT;
    float*  qsoa  = ws + OFF_QSOA;
    float*  qsf   = ws + OFF_QSF;
    half_t* gmat  = (half_t*)(ws + OFF_G);
    half_t* qh16  = (half_t*)(ws + OFF_QH16);
    half_t* part  = (half_t*)(ws + OFF_PART);

    // iteration 0: fused setup+bilat+conv (separate kernel, isolated regalloc)
    iter0_kernel<<<NBTOT, 256, 0, stream>>>(
        unary, ref, kstd, part, qsf, qsoa, qfeat, gmat);
    reduce_update_kernel<<<256, 256, 0, stream>>>(
        part, unary, qsf, outq, qh16, 0);
    // iterations 1..4: R6-proven staged kernels
    for (int it = 1; it < NUM_ITER; ++it) {
        bilat_conv_kernel<<<NBTOT, 256, 0, stream>>>(
            qfeat, qsoa, qh16, gmat, part, qsf);
        reduce_update_kernel<<<256, 256, 0, stream>>>(
            part, unary, qsf, outq, qh16, it == NUM_ITER - 1 ? 1 : 0);
    }
}

// Round 12
// 161.131 us; speedup vs baseline: 1.5985x; 1.1446x over previous
//
#include <hip/hip_runtime.h>
#include <math.h>

#ifndef __has_builtin
#define __has_builtin(x) 0
#endif
#if __has_builtin(__builtin_amdgcn_exp2f)
#define EXP2F(x) __builtin_amdgcn_exp2f(x)
#else
#define EXP2F(x) exp2f(x)
#endif

#define L2E  1.44269504088896340736f
#define RL2E 0.69314718055994530942f

#define NBATCH 2
#define NC 21
#define NP 4096
#define KR 35
#define NUM_ITER 5

typedef _Float16 half_t;
typedef _Float16 h8 __attribute__((ext_vector_type(8)));
typedef _Float16 h4 __attribute__((ext_vector_type(4)));
typedef float f4 __attribute__((ext_vector_type(4)));
typedef float f2 __attribute__((ext_vector_type(2)));
#define MFMA16(a, b, c) __builtin_amdgcn_mfma_f32_16x16x32_f16((a), (b), (c), 0, 0, 0)

// packed fp32 math via inline asm (builtin lowering NaN'd — R8/R13)
static __device__ __forceinline__ f2 pk_fma(f2 a, f2 b, f2 c) {
    f2 d;
    asm volatile("v_pk_fma_f32 %0, %1, %2, %3" : "=v"(d) : "v"(a), "v"(b), "v"(c));
    return d;
}
static __device__ __forceinline__ f2 pk_add(f2 a, f2 b) {
    f2 d;
    asm volatile("v_pk_add_f32 %0, %1, %2" : "=v"(d) : "v"(a), "v"(b));
    return d;
}

// ---- tiling: R6-proven (PTILE=256, 4 m-tiles/wave; best measured 144.4) ----
#define PTILE 256
#define NPT   16
#define MTW   4
#define SQ    16
#define CHUNK 256
#define STEPS 8
#define NBBIL (NBATCH * NPT * SQ)   // 512
#define NBCONV (NBATCH * NC)        // 42 -> blocks [0,42): conv FIRST (no tail)
#define NBTOT  (NBBIL + NBCONV)     // 554
#define SEG_HALVES 256

// ---- ws layout (float offsets) — R6 verbatim ----
#define OFF_QFEAT 0                  // [8192][8] fp32 AoS p-features
#define OFF_QSOA  65536              // [6][8192] fp32 SoA q-feature planes
#define OFF_UT    114688             // [8192][24] fp32 log-unary
#define OFF_QSF   311296             // [NB][21][P] fp32 spatial out
#define OFF_G     483328             // [64][64] fp16 band-gaussian
#define OFF_QH16  485376             // [NB][24][P] fp16 planar q
#define OFF_PART  845824             // [SQ][1024 segs][256] fp16 partials

#define LDS_BYTES 27648
#define QLS_STRIDE 264     // halves (256 data + 8 pad) — R6-proven banking

// setup: 128 blocks x 64 threads (4x CU coverage vs 32x256; per-thread math
// BIT-IDENTICAL to R6 — only the gid decomposition changes).
__global__ __launch_bounds__(64) void setup_kernel(
    const float* __restrict__ unary, const float* __restrict__ ref,
    const float* __restrict__ kstd, float* __restrict__ ws,
    float* __restrict__ outq)
{
    int gid = blockIdx.x * 64 + threadIdx.x;
    if (gid < 4096) {
        float s = 0.f;
        for (int t = -KR; t <= KR; ++t) s += expf(-(float)(t * t) * (1.0f / 72.0f));
        int y = gid >> 6, yp = gid & 63;
        int d = y - yp;
        float v = (d >= -KR && d <= KR) ? expf(-(float)(d * d) * (1.0f / 72.0f)) / s : 0.f;
        ((half_t*)(ws + OFF_G))[gid] = (half_t)v;
    }
    if (gid >= NBATCH * NP) return;
    int n = gid >> 12, p = gid & (NP - 1);
    int y = p >> 6, x = p & 63;
    float k0 = kstd[0], k1 = kstd[1], k2 = kstd[2], k3 = kstd[3], k4 = kstd[4];
    const float* rp = ref + n * 3 * NP + p;
    float f0 = (float)y / k0;
    float f1 = (float)x / k1;
    float f2_ = rp[0]      / k2;
    float f3 = rp[NP]     / k3;
    float f4_ = rp[2 * NP] / k4;
    float sq = f0*f0 + f1*f1 + f2_*f2_ + f3*f3 + f4_*f4_;
    float h  = -0.5f * L2E * sq;       // exp2 exponent offset
    float* qf = ws + OFF_QFEAT + gid * 8;
    qf[0]=L2E*f0; qf[1]=L2E*f1; qf[2]=L2E*f2_; qf[3]=L2E*f3; qf[4]=L2E*f4_;
    qf[5]=h; qf[6]=0.f; qf[7]=0.f;
    float* qs = ws + OFF_QSOA;
    qs[0*8192 + gid] = L2E*f0;  qs[1*8192 + gid] = L2E*f1;
    qs[2*8192 + gid] = L2E*f2_; qs[3*8192 + gid] = L2E*f3;
    qs[4*8192 + gid] = L2E*f4_; qs[5*8192 + gid] = h;

    float U[NC], e[NC];
    const float* up = unary + n * NC * NP + p;
    float m = -1e30f;
    for (int c = 0; c < NC; ++c) {
        float u = up[c * NP];
        u = fminf(fmaxf(u, 1e-5f), 1.0f);
        U[c] = logf(u);
        m = fmaxf(m, U[c]);
    }
    float ssum = 0.f;
    for (int c = 0; c < NC; ++c) { e[c] = EXP2F(L2E * (U[c] - m)); ssum += e[c]; }
    float inv = 1.0f / ssum;
    float* ut = ws + OFF_UT + gid * 24;
    half_t* qh = (half_t*)(ws + OFF_QH16);
    for (int c = 0; c < NC; ++c) {
        float qv = e[c] * inv;
        ut[c] = U[c];
        qh[(n * 24 + c) * NP + p] = (half_t)qv;
        outq[(n * NC + c) * NP + p] = qv;
    }
    ut[21] = 0.f; ut[22] = 0.f; ut[23] = 0.f;
    qh[(n * 24 + 21) * NP + p] = (half_t)0.f;
    qh[(n * 24 + 22) * NP + p] = (half_t)0.f;
    qh[(n * 24 + 23) * NP + p] = (half_t)0.f;
}

// L1: blocks [0,42): separable conv (FIRST -> co-resident, no tail).
//     blocks [42,554): bilateral, R6-verbatim body.
__global__ __launch_bounds__(256) void bilat_conv_kernel(
    const float* __restrict__ qfeatA,     // AoS (p side)
    const float* __restrict__ qsoa,       // SoA planes (q side)
    const half_t* __restrict__ qh16,
    const half_t* __restrict__ gmat,
    half_t* __restrict__ part,
    float* __restrict__ qsf)
{
    __shared__ __align__(16) char lds[LDS_BYTES];
    int b = blockIdx.x;
    int tid = threadIdx.x;
    int l = tid & 63, w = tid >> 6;

    if (b >= NBCONV) {
        int bb = b - NBCONV;
        int n  = bb & 1;
        int pt = (bb >> 1) & (NPT - 1);            // 0..15
        int s  = bb >> 5;                          // 0..15
        float*  qsoaS = (float*)lds;               // [6][256]  6 KB
        half_t* qls   = (half_t*)(lds + 6144);     // [32][264] 16896 B

        // stage SoA q-features (coalesced per plane)
        for (int i = tid; i < 6 * (CHUNK / 4); i += 256) {   // 384 float4
            int d = i >> 6, g = i & 63;
            *(f4*)(qsoaS + d * CHUNK + g * 4) =
                *(const f4*)(qsoa + (size_t)d * 8192 + n * NP + s * CHUNK + g * 4);
        }
        // stage q-probs fp16 rows 0..20; zero rows 21..31
        for (int i = tid; i < 21 * (CHUNK / 8); i += 256) {  // 672 h8
            int c = i >> 5, g = i & 31;
            *(h8*)(qls + c * QLS_STRIDE + g * 8) =
                *(const h8*)(qh16 + (size_t)(n * 24 + c) * NP + s * CHUNK + g * 8);
        }
        for (int i = tid; i < 11 * 33; i += 256) {           // 363 h8 zeros
            int c = 21 + i / 33, g = i % 33;
            *(h8*)(qls + c * QLS_STRIDE + g * 8) = (h8)(half_t)0.f;
        }
        // p-side features: wave w owns m-tiles w*4+mt; lane row = l&15
        f2 pf2[MTW][5], ph2[MTW];
        #pragma unroll
        for (int mt = 0; mt < MTW; ++mt) {
            const float* fp = qfeatA + (size_t)(n * NP + pt * PTILE + (w * MTW + mt) * 16 + (l & 15)) * 8;
            #pragma unroll
            for (int i = 0; i < 5; ++i) {
                float v = fp[i] * RL2E;
                pf2[mt][i] = (f2){v, v};
            }
            ph2[mt] = (f2){fp[5], fp[5]};
        }
        f4 acc[MTW][2];
        #pragma unroll
        for (int mt = 0; mt < MTW; ++mt) { acc[mt][0] = (f4)0.f; acc[mt][1] = (f4)0.f; }
        int kq = (l >> 4) * 8;
        __syncthreads();

        for (int step = 0; step < STEPS; ++step) {
            int qbase = step * 32 + kq;
            h8 kv[MTW];
            #pragma unroll
            for (int hf = 0; hf < 2; ++hf) {
                // conflict-free b128 quad reads: this lane's 4 q's, all 6 features
                f4 qf0 = *(const f4*)(qsoaS + 0 * CHUNK + qbase + hf * 4);
                f4 qf1 = *(const f4*)(qsoaS + 1 * CHUNK + qbase + hf * 4);
                f4 qf2 = *(const f4*)(qsoaS + 2 * CHUNK + qbase + hf * 4);
                f4 qf3 = *(const f4*)(qsoaS + 3 * CHUNK + qbase + hf * 4);
                f4 qf4 = *(const f4*)(qsoaS + 4 * CHUNK + qbase + hf * 4);
                f4 qf5 = *(const f4*)(qsoaS + 5 * CHUNK + qbase + hf * 4);
                // packed fp32 fma via asm: two q's per instruction
                #pragma unroll
                for (int pr = 0; pr < 2; ++pr) {
                    f2 q0 = {qf0[2*pr], qf0[2*pr+1]};
                    f2 q1 = {qf1[2*pr], qf1[2*pr+1]};
                    f2 q2 = {qf2[2*pr], qf2[2*pr+1]};
                    f2 q3 = {qf3[2*pr], qf3[2*pr+1]};
                    f2 q4 = {qf4[2*pr], qf4[2*pr+1]};
                    f2 qh2 = {qf5[2*pr], qf5[2*pr+1]};
                    #pragma unroll
                    for (int mt = 0; mt < MTW; ++mt) {
                        f2 e = pk_add(qh2, ph2[mt]);
                        e = pk_fma(pf2[mt][0], q0, e);
                        e = pk_fma(pf2[mt][1], q1, e);
                        e = pk_fma(pf2[mt][2], q2, e);
                        e = pk_fma(pf2[mt][3], q3, e);
                        e = pk_fma(pf2[mt][4], q4, e);
                        kv[mt][hf * 4 + pr * 2]     = (half_t)EXP2F(e[0]);
                        kv[mt][hf * 4 + pr * 2 + 1] = (half_t)EXP2F(e[1]);
                    }
                }
            }
            h8 bf0 = *(const h8*)(qls + (size_t)(l & 15) * QLS_STRIDE + qbase);
            h8 bf1 = *(const h8*)(qls + (size_t)(16 + (l & 15)) * QLS_STRIDE + qbase);
            #pragma unroll
            for (int mt = 0; mt < MTW; ++mt) {
                acc[mt][0] = MFMA16(kv[mt], bf0, acc[mt][0]);
                acc[mt][1] = MFMA16(kv[mt], bf1, acc[mt][1]);
            }
        }
        // epilogue: raw C-fragment partials, fp16, coalesced b64
        // seg = (s*2+n)*512 + pt*32 + w*8 + mt*2 + cht  (R6 verbatim)
        #pragma unroll
        for (int mt = 0; mt < MTW; ++mt) {
            #pragma unroll
            for (int cht = 0; cht < 2; ++cht) {
                int segFlat = ((((s * 2 + n) * NPT + pt) * 4 + w) * MTW + mt) * 2 + cht;
                h4 hv;
                hv[0] = (half_t)acc[mt][cht][0];
                hv[1] = (half_t)acc[mt][cht][1];
                hv[2] = (half_t)acc[mt][cht][2];
                hv[3] = (half_t)acc[mt][cht][3];
                *(h4*)(part + (size_t)segFlat * SEG_HALVES + l * 4) = hv;
            }
        }
    } else {
        // ---- conv block: one (n,c); qsf = G * Q * G (R6 verbatim body) ----
        int n = b / NC, c = b % NC;
        half_t* qt = (half_t*)lds;
        half_t* gl = (half_t*)(lds + 9216);
        half_t* dl = (half_t*)(lds + 18432);

        for (int i = tid; i < 512; i += 256) {
            int row = i >> 3, g = i & 7;
            *(h8*)(gl + row * 72 + g * 8) = *(const h8*)(gmat + row * 64 + g * 8);
        }
        const half_t* qsrc = qh16 + (size_t)(n * 24 + c) * NP;
        for (int i = tid; i < 512; i += 256) {
            int row = i >> 3, g = i & 7;
            h8 v = *(const h8*)(qsrc + row * 64 + g * 8);
            #pragma unroll
            for (int k = 0; k < 8; ++k) qt[(g * 8 + k) * 72 + row] = v[k];
        }
        __syncthreads();

        int m0 = w * 16;
        f4 acc1[4];
        #pragma unroll
        for (int nt = 0; nt < 4; ++nt) acc1[nt] = (f4)0.f;
        #pragma unroll
        for (int ks = 0; ks < 2; ++ks) {
            h8 af = *(const h8*)(gl + (size_t)(m0 + (l & 15)) * 72 + ks * 32 + (l >> 4) * 8);
            #pragma unroll
            for (int nt = 0; nt < 4; ++nt) {
                h8 bf = *(const h8*)(qt + (size_t)(nt * 16 + (l & 15)) * 72 + ks * 32 + (l >> 4) * 8);
                acc1[nt] = MFMA16(af, bf, acc1[nt]);
            }
        }
        #pragma unroll
        for (int nt = 0; nt < 4; ++nt)
            #pragma unroll
            for (int r = 0; r < 4; ++r)
                dl[(size_t)(m0 + (l >> 4) * 4 + r) * 72 + nt * 16 + (l & 15)] = (half_t)acc1[nt][r];
        __syncthreads();

        f4 acc2[4];
        #pragma unroll
        for (int nt = 0; nt < 4; ++nt) acc2[nt] = (f4)0.f;
        #pragma unroll
        for (int ks = 0; ks < 2; ++ks) {
            h8 af = *(const h8*)(dl + (size_t)(m0 + (l & 15)) * 72 + ks * 32 + (l >> 4) * 8);
            #pragma unroll
            for (int nt = 0; nt < 4; ++nt) {
                h8 bf = *(const h8*)(gl + (size_t)(nt * 16 + (l & 15)) * 72 + ks * 32 + (l >> 4) * 8);
                acc2[nt] = MFMA16(af, bf, acc2[nt]);
            }
        }
        float* dst = qsf + (size_t)(n * NC + c) * NP;
        #pragma unroll
        for (int nt = 0; nt < 4; ++nt)
            #pragma unroll
            for (int r = 0; r < 4; ++r)
                dst[(size_t)(m0 + (l >> 4) * 4 + r) * 64 + nt * 16 + (l & 15)] = acc2[nt][r];
    }
}

// L2+L3 merged: reduce fp16 partials over s, then per-pixel softmax update.
// R6 verbatim (256 blocks, register-preloaded s-partials, original s-order).
__global__ __launch_bounds__(256) void reduce_update_kernel(
    const half_t* __restrict__ part, const float* __restrict__ ut_,
    const float* __restrict__ qsf, float* __restrict__ outq,
    half_t* __restrict__ qh16, int last)
{
    __shared__ float red[1024];    // 4 segs * 256
    int rb = blockIdx.x;           // [0,256)
    int tid = threadIdx.x;
    int n = rb & 1, pt = (rb >> 1) & (NPT - 1), wq = rb >> 5;   // wq 0..7
    int w = wq >> 1, mtbase = (wq & 1) * 2;
    int lseg = tid >> 6, l = tid & 63;   // lseg = mtl*2 + cht

    // seg(s) = (s*2+n)*512 + pt*32 + w*8 + mtbase*2 + lseg
    const half_t* pb = part
        + (size_t)(n * 512 + pt * 32 + w * 8 + mtbase * 2 + lseg) * SEG_HALVES
        + (size_t)l * 4;
    h4 vv[16];
    #pragma unroll
    for (int s = 0; s < SQ; ++s)
        vv[s] = *(const h4*)(pb + (size_t)s * 1024 * SEG_HALVES);

    float a0 = 0.f, a1 = 0.f, a2 = 0.f, a3 = 0.f;
    #pragma unroll
    for (int s = 0; s < SQ; ++s) {            // same s-order as R4/R6
        a0 += (float)vv[s][0]; a1 += (float)vv[s][1];
        a2 += (float)vv[s][2]; a3 += (float)vv[s][3];
    }
    *(f4*)(red + tid * 4) = (f4){a0, a1, a2, a3};
    __syncthreads();

    if (tid < 32) {
        int pp = tid;
        int p = pt * PTILE + wq * 32 + pp;
        int gid = n * NP + p;
        int mtl = pp >> 4, mrow = pp & 15;
        int lg2 = mrow >> 2, reg = mrow & 3;

        const float* ut = ut_ + (size_t)gid * 24;
        const float* qs = qsf + (size_t)n * NC * NP + p;
        float e[NC];
        float m = -1e30f;
        #pragma unroll
        for (int c = 0; c < NC; ++c) {
            int cht = c >> 4, chL = c & 15;
            float qb = red[(mtl * 2 + cht) * 256 + (lg2 * 16 + chL) * 4 + reg];
            float li = ut[c] + 4.0f * qb + 2.0f * qs[c * NP];
            e[c] = li;
            m = fmaxf(m, li);
        }
        float ssum = 0.f;
        #pragma unroll
        for (int c = 0; c < NC; ++c) { float v = EXP2F(L2E * (e[c] - m)); e[c] = v; ssum += v; }
        float inv = 1.0f / ssum;
        if (last) {
            #pragma unroll
            for (int c = 0; c < NC; ++c)
                outq[(size_t)(n * NC + c) * NP + p] = e[c] * inv;
        } else {
            #pragma unroll
            for (int c = 0; c < NC; ++c)
                qh16[(size_t)(n * 24 + c) * NP + p] = (half_t)(e[c] * inv);
        }
    }
}

extern "C" void kernel_launch(void* const* d_in, const int* in_sizes, int n_in,
                              void* d_out, int out_size, void* d_ws, size_t ws_size,
                              hipStream_t stream)
{
    const float* unary = (const float*)d_in[0];
    const float* ref   = (const float*)d_in[1];
    const float* kstd  = (const float*)d_in[3];
    float* ws   = (float*)d_ws;
    float* outq = (float*)d_out;

    const float*  qfeatA = ws + OFF_QFEAT;
    const float*  qsoa   = ws + OFF_QSOA;
    float*        ut     = ws + OFF_UT;
    float*        qsf    = ws + OFF_QSF;
    const half_t* gmat   = (const half_t*)(ws + OFF_G);
    half_t*       qh16   = (half_t*)(ws + OFF_QH16);
    half_t*       part   = (half_t*)(ws + OFF_PART);

    setup_kernel<<<128, 64, 0, stream>>>(unary, ref, kstd, ws, outq);
    for (int it = 0; it < NUM_ITER; ++it) {
        bilat_conv_kernel<<<NBTOT, 256, 0, stream>>>(
            qfeatA, qsoa, qh16, gmat, part, qsf);
        reduce_update_kernel<<<256, 256, 0, stream>>>(
            part, ut, qsf, outq, qh16, it == NUM_ITER - 1 ? 1 : 0);
    }
}

// Round 13
// 144.569 us; speedup vs baseline: 1.7817x; 1.1146x over previous
//
#include <hip/hip_runtime.h>
#include <math.h>

#ifndef __has_builtin
#define __has_builtin(x) 0
#endif
#if __has_builtin(__builtin_amdgcn_exp2f)
#define EXP2F(x) __builtin_amdgcn_exp2f(x)
#else
#define EXP2F(x) exp2f(x)
#endif

#define L2E  1.44269504088896340736f
#define RL2E 0.69314718055994530942f

#define NBATCH 2
#define NC 21
#define NP 4096
#define KR 35
#define NUM_ITER 5

typedef _Float16 half_t;
typedef _Float16 h8 __attribute__((ext_vector_type(8)));
typedef _Float16 h4 __attribute__((ext_vector_type(4)));
typedef float f4 __attribute__((ext_vector_type(4)));
typedef float f2 __attribute__((ext_vector_type(2)));
#define MFMA16(a, b, c) __builtin_amdgcn_mfma_f32_16x16x32_f16((a), (b), (c), 0, 0, 0)

// packed fp32 math via inline asm (builtin lowering NaN'd — R8/R13)
static __device__ __forceinline__ f2 pk_fma(f2 a, f2 b, f2 c) {
    f2 d;
    asm volatile("v_pk_fma_f32 %0, %1, %2, %3" : "=v"(d) : "v"(a), "v"(b), "v"(c));
    return d;
}
static __device__ __forceinline__ f2 pk_add(f2 a, f2 b) {
    f2 d;
    asm volatile("v_pk_add_f32 %0, %1, %2" : "=v"(d) : "v"(a), "v"(b));
    return d;
}

// ---- tiling: R6-proven (PTILE=256, 4 m-tiles/wave; best measured 144.4) ----
#define PTILE 256
#define NPT   16
#define MTW   4
#define SQ    16
#define CHUNK 256
#define STEPS 8
#define NBBIL (NBATCH * NPT * SQ)   // 512
#define NBCONV (NBATCH * NC)        // 42  (conv LAST: overflow round = short blocks)
#define NBTOT  (NBBIL + NBCONV)     // 554
#define SEG_HALVES 256

// ---- ws layout (float offsets) ----
#define OFF_QFEAT 0                  // [8192][8] fp32 AoS p-features
#define OFF_QSOA  65536              // [6][8192] fp32 SoA q-feature planes
#define OFF_UT    114688             // [8192][24] fp32 log-unary
#define OFF_QSF   311296             // [NB][21][P] fp32 spatial out
#define OFF_G     483328             // [64][64] fp16 band-gaussian
#define OFF_QH16  485376             // [NB][24][P] fp16 planar q
#define OFF_PART  845824             // [SQ][1024 segs][256] fp16 partials

#define LDS_BYTES 27648
#define QLS_STRIDE 264     // halves (256 data + 8 pad) — R6-proven banking

__global__ __launch_bounds__(256) void setup_kernel(
    const float* __restrict__ unary, const float* __restrict__ ref,
    const float* __restrict__ kstd, float* __restrict__ ws,
    float* __restrict__ outq)
{
    int gid = blockIdx.x * 256 + threadIdx.x;
    if (gid < 4096) {
        float s = 0.f;
        for (int t = -KR; t <= KR; ++t) s += expf(-(float)(t * t) * (1.0f / 72.0f));
        int y = gid >> 6, yp = gid & 63;
        int d = y - yp;
        float v = (d >= -KR && d <= KR) ? expf(-(float)(d * d) * (1.0f / 72.0f)) / s : 0.f;
        ((half_t*)(ws + OFF_G))[gid] = (half_t)v;
    }
    if (gid >= NBATCH * NP) return;
    int n = gid >> 12, p = gid & (NP - 1);
    int y = p >> 6, x = p & 63;
    float k0 = kstd[0], k1 = kstd[1], k2 = kstd[2], k3 = kstd[3], k4 = kstd[4];
    const float* rp = ref + n * 3 * NP + p;
    float f0 = (float)y / k0;
    float f1 = (float)x / k1;
    float f2_ = rp[0]      / k2;
    float f3 = rp[NP]     / k3;
    float f4_ = rp[2 * NP] / k4;
    float sq = f0*f0 + f1*f1 + f2_*f2_ + f3*f3 + f4_*f4_;
    float h  = -0.5f * L2E * sq;       // exp2 exponent offset
    float* qf = ws + OFF_QFEAT + gid * 8;
    qf[0]=L2E*f0; qf[1]=L2E*f1; qf[2]=L2E*f2_; qf[3]=L2E*f3; qf[4]=L2E*f4_;
    qf[5]=h; qf[6]=0.f; qf[7]=0.f;
    float* qs = ws + OFF_QSOA;
    qs[0*8192 + gid] = L2E*f0;  qs[1*8192 + gid] = L2E*f1;
    qs[2*8192 + gid] = L2E*f2_; qs[3*8192 + gid] = L2E*f3;
    qs[4*8192 + gid] = L2E*f4_; qs[5*8192 + gid] = h;

    float U[NC], e[NC];
    const float* up = unary + n * NC * NP + p;
    float m = -1e30f;
    for (int c = 0; c < NC; ++c) {
        float u = up[c * NP];
        u = fminf(fmaxf(u, 1e-5f), 1.0f);
        U[c] = logf(u);
        m = fmaxf(m, U[c]);
    }
    float ssum = 0.f;
    for (int c = 0; c < NC; ++c) { e[c] = EXP2F(L2E * (U[c] - m)); ssum += e[c]; }
    float inv = 1.0f / ssum;
    float* ut = ws + OFF_UT + gid * 24;
    half_t* qh = (half_t*)(ws + OFF_QH16);
    for (int c = 0; c < NC; ++c) {
        float qv = e[c] * inv;
        ut[c] = U[c];
        qh[(n * 24 + c) * NP + p] = (half_t)qv;
        outq[(n * NC + c) * NP + p] = qv;
    }
    ut[21] = 0.f; ut[22] = 0.f; ut[23] = 0.f;
    qh[(n * 24 + 21) * NP + p] = (half_t)0.f;
    qh[(n * 24 + 22) * NP + p] = (half_t)0.f;
    qh[(n * 24 + 23) * NP + p] = (half_t)0.f;
}

// L1: blocks [0,512): bilateral (PTILE=256). blocks [512,554): separable conv.
__global__ __launch_bounds__(256) void bilat_conv_kernel(
    const float* __restrict__ qfeatA,     // AoS (p side)
    const float* __restrict__ qsoa,       // SoA planes (q side)
    const half_t* __restrict__ qh16,
    const half_t* __restrict__ gmat,
    half_t* __restrict__ part,
    float* __restrict__ qsf)
{
    __shared__ __align__(16) char lds[LDS_BYTES];
    int b = blockIdx.x;
    int tid = threadIdx.x;
    int l = tid & 63, w = tid >> 6;

    if (b < NBBIL) {
        int n  = b & 1;
        int pt = (b >> 1) & (NPT - 1);             // 0..15
        int s  = b >> 5;                           // 0..15
        float*  qsoaS = (float*)lds;               // [6][256]  6 KB
        half_t* qls   = (half_t*)(lds + 6144);     // [32][264] 16896 B

        // stage SoA q-features (coalesced per plane)
        for (int i = tid; i < 6 * (CHUNK / 4); i += 256) {   // 384 float4
            int d = i >> 6, g = i & 63;
            *(f4*)(qsoaS + d * CHUNK + g * 4) =
                *(const f4*)(qsoa + (size_t)d * 8192 + n * NP + s * CHUNK + g * 4);
        }
        // stage q-probs fp16 rows 0..20; zero rows 21..31
        for (int i = tid; i < 21 * (CHUNK / 8); i += 256) {  // 672 h8
            int c = i >> 5, g = i & 31;
            *(h8*)(qls + c * QLS_STRIDE + g * 8) =
                *(const h8*)(qh16 + (size_t)(n * 24 + c) * NP + s * CHUNK + g * 8);
        }
        for (int i = tid; i < 11 * 33; i += 256) {           // 363 h8 zeros
            int c = 21 + i / 33, g = i % 33;
            *(h8*)(qls + c * QLS_STRIDE + g * 8) = (h8)(half_t)0.f;
        }
        // p-side features: wave w owns m-tiles w*4+mt (mt=0..3); lane row = l&15
        f2 pf2[MTW][5], ph2[MTW];
        #pragma unroll
        for (int mt = 0; mt < MTW; ++mt) {
            const float* fp = qfeatA + (size_t)(n * NP + pt * PTILE + (w * MTW + mt) * 16 + (l & 15)) * 8;
            #pragma unroll
            for (int i = 0; i < 5; ++i) {
                float v = fp[i] * RL2E;
                pf2[mt][i] = (f2){v, v};
            }
            ph2[mt] = (f2){fp[5], fp[5]};
        }
        f4 acc[MTW][2];
        #pragma unroll
        for (int mt = 0; mt < MTW; ++mt) { acc[mt][0] = (f4)0.f; acc[mt][1] = (f4)0.f; }
        int kq = (l >> 4) * 8;
        __syncthreads();

        for (int step = 0; step < STEPS; ++step) {
            int qbase = step * 32 + kq;
            h8 kv[MTW];
            #pragma unroll
            for (int hf = 0; hf < 2; ++hf) {
                // conflict-free b128 quad reads: this lane's 4 q's, all 6 features
                f4 qf0 = *(const f4*)(qsoaS + 0 * CHUNK + qbase + hf * 4);
                f4 qf1 = *(const f4*)(qsoaS + 1 * CHUNK + qbase + hf * 4);
                f4 qf2 = *(const f4*)(qsoaS + 2 * CHUNK + qbase + hf * 4);
                f4 qf3 = *(const f4*)(qsoaS + 3 * CHUNK + qbase + hf * 4);
                f4 qf4 = *(const f4*)(qsoaS + 4 * CHUNK + qbase + hf * 4);
                f4 qf5 = *(const f4*)(qsoaS + 5 * CHUNK + qbase + hf * 4);
                // packed fp32 fma via asm: two q's per instruction
                #pragma unroll
                for (int pr = 0; pr < 2; ++pr) {
                    f2 q0 = {qf0[2*pr], qf0[2*pr+1]};
                    f2 q1 = {qf1[2*pr], qf1[2*pr+1]};
                    f2 q2 = {qf2[2*pr], qf2[2*pr+1]};
                    f2 q3 = {qf3[2*pr], qf3[2*pr+1]};
                    f2 q4 = {qf4[2*pr], qf4[2*pr+1]};
                    f2 qh2 = {qf5[2*pr], qf5[2*pr+1]};
                    #pragma unroll
                    for (int mt = 0; mt < MTW; ++mt) {
                        f2 e = pk_add(qh2, ph2[mt]);
                        e = pk_fma(pf2[mt][0], q0, e);
                        e = pk_fma(pf2[mt][1], q1, e);
                        e = pk_fma(pf2[mt][2], q2, e);
                        e = pk_fma(pf2[mt][3], q3, e);
                        e = pk_fma(pf2[mt][4], q4, e);
                        kv[mt][hf * 4 + pr * 2]     = (half_t)EXP2F(e[0]);
                        kv[mt][hf * 4 + pr * 2 + 1] = (half_t)EXP2F(e[1]);
                    }
                }
            }
            h8 bf0 = *(const h8*)(qls + (size_t)(l & 15) * QLS_STRIDE + qbase);
            h8 bf1 = *(const h8*)(qls + (size_t)(16 + (l & 15)) * QLS_STRIDE + qbase);
            #pragma unroll
            for (int mt = 0; mt < MTW; ++mt) {
                acc[mt][0] = MFMA16(kv[mt], bf0, acc[mt][0]);
                acc[mt][1] = MFMA16(kv[mt], bf1, acc[mt][1]);
            }
        }
        // epilogue: raw C-fragment partials, fp16, coalesced b64
        // seg = (s*2+n)*512 + pt*32 + w*8 + mt*2 + cht
        #pragma unroll
        for (int mt = 0; mt < MTW; ++mt) {
            #pragma unroll
            for (int cht = 0; cht < 2; ++cht) {
                int segFlat = ((((s * 2 + n) * NPT + pt) * 4 + w) * MTW + mt) * 2 + cht;
                h4 hv;
                hv[0] = (half_t)acc[mt][cht][0];
                hv[1] = (half_t)acc[mt][cht][1];
                hv[2] = (half_t)acc[mt][cht][2];
                hv[3] = (half_t)acc[mt][cht][3];
                *(h4*)(part + (size_t)segFlat * SEG_HALVES + l * 4) = hv;
            }
        }
    } else {
        // ---- conv block: one (n,c); qsf = G * Q * G ----
        int cb = b - NBBIL;
        int n = cb / NC, c = cb % NC;
        half_t* qt = (half_t*)lds;
        half_t* gl = (half_t*)(lds + 9216);
        half_t* dl = (half_t*)(lds + 18432);

        for (int i = tid; i < 512; i += 256) {
            int row = i >> 3, g = i & 7;
            *(h8*)(gl + row * 72 + g * 8) = *(const h8*)(gmat + row * 64 + g * 8);
        }
        const half_t* qsrc = qh16 + (size_t)(n * 24 + c) * NP;
        for (int i = tid; i < 512; i += 256) {
            int row = i >> 3, g = i & 7;
            h8 v = *(const h8*)(qsrc + row * 64 + g * 8);
            #pragma unroll
            for (int k = 0; k < 8; ++k) qt[(g * 8 + k) * 72 + row] = v[k];
        }
        __syncthreads();

        int m0 = w * 16;
        f4 acc1[4];
        #pragma unroll
        for (int nt = 0; nt < 4; ++nt) acc1[nt] = (f4)0.f;
        #pragma unroll
        for (int ks = 0; ks < 2; ++ks) {
            h8 af = *(const h8*)(gl + (size_t)(m0 + (l & 15)) * 72 + ks * 32 + (l >> 4) * 8);
            #pragma unroll
            for (int nt = 0; nt < 4; ++nt) {
                h8 bf = *(const h8*)(qt + (size_t)(nt * 16 + (l & 15)) * 72 + ks * 32 + (l >> 4) * 8);
                acc1[nt] = MFMA16(af, bf, acc1[nt]);
            }
        }
        #pragma unroll
        for (int nt = 0; nt < 4; ++nt)
            #pragma unroll
            for (int r = 0; r < 4; ++r)
                dl[(size_t)(m0 + (l >> 4) * 4 + r) * 72 + nt * 16 + (l & 15)] = (half_t)acc1[nt][r];
        __syncthreads();

        f4 acc2[4];
        #pragma unroll
        for (int nt = 0; nt < 4; ++nt) acc2[nt] = (f4)0.f;
        #pragma unroll
        for (int ks = 0; ks < 2; ++ks) {
            h8 af = *(const h8*)(dl + (size_t)(m0 + (l & 15)) * 72 + ks * 32 + (l >> 4) * 8);
            #pragma unroll
            for (int nt = 0; nt < 4; ++nt) {
                h8 bf = *(const h8*)(gl + (size_t)(nt * 16 + (l & 15)) * 72 + ks * 32 + (l >> 4) * 8);
                acc2[nt] = MFMA16(af, bf, acc2[nt]);
            }
        }
        float* dst = qsf + (size_t)(n * NC + c) * NP;
        #pragma unroll
        for (int nt = 0; nt < 4; ++nt)
            #pragma unroll
            for (int r = 0; r < 4; ++r)
                dst[(size_t)(m0 + (l >> 4) * 4 + r) * 64 + nt * 16 + (l & 15)] = acc2[nt][r];
    }
}

// L2+L3 merged: reduce fp16 partials over s, then per-pixel softmax update.
// 256 blocks: rb -> (n, pt in [0,16), wq in [0,8)); 32 p's per block.
// 16 s-partials preloaded to regs (independent loads), summed in the
// ORIGINAL s-order -> bit-identical.
__global__ __launch_bounds__(256) void reduce_update_kernel(
    const half_t* __restrict__ part, const float* __restrict__ ut_,
    const float* __restrict__ qsf, float* __restrict__ outq,
    half_t* __restrict__ qh16, int last)
{
    __shared__ float red[1024];    // 4 segs * 256
    int rb = blockIdx.x;           // [0,256)
    int tid = threadIdx.x;
    int n = rb & 1, pt = (rb >> 1) & (NPT - 1), wq = rb >> 5;   // wq 0..7
    int w = wq >> 1, mtbase = (wq & 1) * 2;
    int lseg = tid >> 6, l = tid & 63;   // lseg = mtl*2 + cht

    // seg(s) = (s*2+n)*512 + pt*32 + w*8 + mtbase*2 + lseg
    const half_t* pb = part
        + (size_t)(n * 512 + pt * 32 + w * 8 + mtbase * 2 + lseg) * SEG_HALVES
        + (size_t)l * 4;
    h4 vv[16];
    #pragma unroll
    for (int s = 0; s < SQ; ++s)
        vv[s] = *(const h4*)(pb + (size_t)s * 1024 * SEG_HALVES);

    float a0 = 0.f, a1 = 0.f, a2 = 0.f, a3 = 0.f;
    #pragma unroll
    for (int s = 0; s < SQ; ++s) {            // same s-order as R4
        a0 += (float)vv[s][0]; a1 += (float)vv[s][1];
        a2 += (float)vv[s][2]; a3 += (float)vv[s][3];
    }
    *(f4*)(red + tid * 4) = (f4){a0, a1, a2, a3};
    __syncthreads();

    if (tid < 32) {
        int pp = tid;
        int p = pt * PTILE + wq * 32 + pp;
        int gid = n * NP + p;
        int mtl = pp >> 4, mrow = pp & 15;
        int lg2 = mrow >> 2, reg = mrow & 3;

        const float* ut = ut_ + (size_t)gid * 24;
        const float* qs = qsf + (size_t)n * NC * NP + p;
        float e[NC];
        float m = -1e30f;
        #pragma unroll
        for (int c = 0; c < NC; ++c) {
            int cht = c >> 4, chL = c & 15;
            float qb = red[(mtl * 2 + cht) * 256 + (lg2 * 16 + chL) * 4 + reg];
            float li = ut[c] + 4.0f * qb + 2.0f * qs[c * NP];
            e[c] = li;
            m = fmaxf(m, li);
        }
        float ssum = 0.f;
        #pragma unroll
        for (int c = 0; c < NC; ++c) { float v = EXP2F(L2E * (e[c] - m)); e[c] = v; ssum += v; }
        float inv = 1.0f / ssum;
        if (last) {
            #pragma unroll
            for (int c = 0; c < NC; ++c)
                outq[(size_t)(n * NC + c) * NP + p] = e[c] * inv;
        } else {
            #pragma unroll
            for (int c = 0; c < NC; ++c)
                qh16[(size_t)(n * 24 + c) * NP + p] = (half_t)(e[c] * inv);
        }
    }
}

extern "C" void kernel_launch(void* const* d_in, const int* in_sizes, int n_in,
                              void* d_out, int out_size, void* d_ws, size_t ws_size,
                              hipStream_t stream)
{
    const float* unary = (const float*)d_in[0];
    const float* ref   = (const float*)d_in[1];
    const float* kstd  = (const float*)d_in[3];
    float* ws   = (float*)d_ws;
    float* outq = (float*)d_out;

    const float*  qfeatA = ws + OFF_QFEAT;
    const float*  qsoa   = ws + OFF_QSOA;
    float*        ut     = ws + OFF_UT;
    float*        qsf    = ws + OFF_QSF;
    const half_t* gmat   = (const half_t*)(ws + OFF_G);
    half_t*       qh16   = (half_t*)(ws + OFF_QH16);
    half_t*       part   = (half_t*)(ws + OFF_PART);

    setup_kernel<<<32, 256, 0, stream>>>(unary, ref, kstd, ws, outq);
    for (int it = 0; it < NUM_ITER; ++it) {
        bilat_conv_kernel<<<NBTOT, 256, 0, stream>>>(
            qfeatA, qsoa, qh16, gmat, part, qsf);
        reduce_update_kernel<<<256, 256, 0, stream>>>(
            part, ut, qsf, outq, qh16, it == NUM_ITER - 1 ? 1 : 0);
    }
}